// Round 3
// baseline (240.166 us; speedup 1.0000x reference)
//
#include <hip/hip_runtime.h>
#include <math.h>

// ---------------------------------------------------------------------------
// SO3 convolution. bf16 MFMA GEMM (complex-as-real); Hermitian-half FFT/IFFT.
// Pipeline: k_fft_fwd (Hermitian bf16 out) -> k_wtr(wf) -> k_prep_B
//           -> k_beta_A -> k_gemm (MFMA) -> k_wtr(wi) -> k_inv2
// R8 lesson: fusing fft+prep into one 512-thr kernel spilled (VGPR cap 128,
// 525 MB scratch traffic) -- keep them separate.
// R9: wfT/wiT [bq][t][4] transposes -- big win in k_beta_A.
// R10: k_inv2 streamed FFT passes (VGPR 92->64), 8 blocks/CU -- 68->~40us.
// R11: k_gemm was latency-bound (Mfma 7%, VALU 5%, 2 barriers/iter, no
// prefetch). As-LDS staging was an identity permutation (reader addr ==
// global addr) -> direct short8 A loads; Bs double-buffered, next-iter
// A/B global loads issued right after the single barrier -> latency hides
// under MFMA. 1 barrier/iter instead of 2.
// Workspace: yhb 44.7MB | Ab 4.2MB | zh_T 11.2MB.
//   Xfb (8.4MB) + wfT (698KB) alias zh_T (lifetime fft->gemm, disjoint).
//   wiT (698KB) aliases yhb base (written after gemm, read by inv2).
// ---------------------------------------------------------------------------

typedef unsigned short u16;
typedef unsigned int   u32;
typedef __attribute__((ext_vector_type(8))) short  short8;   // 8 bf16
typedef __attribute__((ext_vector_type(4))) float  floatx4;

constexpr int LTOT = 5456;

constexpr int LB[17] = {0,1,10,35,84,165,286,455,680,969,
                        1330,1771,2300,2925,3654,4495,5456};

__device__ inline u16 f2bf(float f) {
    u32 u = __float_as_uint(f);
    u += 0x7fff + ((u >> 16) & 1);
    return (u16)(u >> 16);
}
__device__ inline u32 pack2bf(float re, float im) {
    return (u32)f2bf(re) | ((u32)f2bf(im) << 16);
}

// ---------------------------------------------------------------------------
// Wigner-table transpose: w[32][LTOT] -> wT[bq(8)][t][4] so a 4-beta group is
// one float4. Grid (22, 8) x 256.
// ---------------------------------------------------------------------------
__global__ __launch_bounds__(256) void k_wtr(const float* __restrict__ w,
                                             float* __restrict__ wT) {
    int t  = blockIdx.x * 256 + threadIdx.x;
    int bq = blockIdx.y;
    if (t < LTOT) {
        float4 v;
        v.x = w[(size_t)(bq * 4 + 0) * LTOT + t];
        v.y = w[(size_t)(bq * 4 + 1) * LTOT + t];
        v.z = w[(size_t)(bq * 4 + 2) * LTOT + t];
        v.w = w[(size_t)(bq * 4 + 3) * LTOT + t];
        *(float4*)(wT + ((size_t)bq * LTOT + t) * 4) = v;
    }
}

// ---------------------------------------------------------------------------
// Forward FFT2 (e^{-i}), radix-2 both passes, 512 threads, one task each.
// Stores ONLY Hermitian-half rows ma 0..15, bf16-packed.
// x: [z][i][b][a][g].   Xfb: [zi*32+b][ma(0..15)][ng] packed bf16 pairs.
// ---------------------------------------------------------------------------
__global__ __launch_bounds__(512) void k_fft_fwd(const float* __restrict__ x,
                                                 u32* __restrict__ Xfb) {
    __shared__ float xs[1056];               // [a][g] stride 33
    __shared__ float Gre[1056], Gim[1056];   // [a][k] stride 33
    __shared__ float Wc[32], Ws[32];
    int tid = threadIdx.x;
    if (tid < 32) {
        float sv, cv;
        sincosf(6.28318530717958647692f * (float)tid / 32.0f, &sv, &cv);
        Wc[tid] = cv; Ws[tid] = sv;
    }
    const float* src = x + (size_t)blockIdx.x * 1024;
    for (int e = tid; e < 1024; e += 512) xs[(e >> 5) * 33 + (e & 31)] = src[e];
    __syncthreads();
    // pass 1 over g (real input), radix-2: task = (a, k in 0..15)
    {
        int a = tid >> 4, k = tid & 15;
        const float* row = &xs[a * 33];
        float Er = 0.f, Ei = 0.f, Or = 0.f, Oi = 0.f;
#pragma unroll
        for (int h = 0; h < 16; h++) {
            int idx = (2 * h * k) & 31;
            float c = Wc[idx], s = Ws[idx];
            float xe = row[2 * h], xo = row[2 * h + 1];
            Er += xe * c;  Ei -= xe * s;
            Or += xo * c;  Oi -= xo * s;
        }
        float WOr = Or * Wc[k] + Oi * Ws[k];
        float WOi = Oi * Wc[k] - Or * Ws[k];
        Gre[a * 33 + k]      = Er + WOr;
        Gim[a * 33 + k]      = Ei + WOi;
        Gre[a * 33 + k + 16] = Er - WOr;
        Gim[a * 33 + k + 16] = Ei - WOi;
    }
    __syncthreads();
    // pass 2 over a, radix-2 combine; store only row ma (0..15)
    {
        u32* dst = Xfb + (size_t)blockIdx.x * 512;
        int ng = tid & 31, ma = tid >> 5;
        float Er = 0.f, Ei = 0.f, Or = 0.f, Oi = 0.f;
#pragma unroll
        for (int h = 0; h < 16; h++) {
            int idx = (2 * h * ma) & 31;
            float c = Wc[idx], s = Ws[idx];
            float er = Gre[(2 * h) * 33 + ng],      ei = Gim[(2 * h) * 33 + ng];
            float orr = Gre[(2 * h + 1) * 33 + ng], oi = Gim[(2 * h + 1) * 33 + ng];
            Er += er * c + ei * s;   Ei += ei * c - er * s;
            Or += orr * c + oi * s;  Oi += oi * c - orr * s;
        }
        float WOr = Or * Wc[ma] + Oi * Ws[ma];
        float WOi = Oi * Wc[ma] - Or * Ws[ma];
        dst[ma * 32 + ng] = pack2bf(Er + WOr, Ei + WOi);
    }
}

// ---------------------------------------------------------------------------
// Build compact bf16 yh: yhb[t2][io] = pack(bf16(re), bf16(im)) of D*kernel.
// (Separate kernel -- R7-proven register footprint.)
// ---------------------------------------------------------------------------
__global__ __launch_bounds__(256) void k_prep_B(const float* __restrict__ Dre,
                                                const float* __restrict__ Dim,
                                                const float* __restrict__ ker,
                                                u32* __restrict__ yhb) {
    __shared__ float Ds[8][24];
    int t0  = blockIdx.x * 8;
    int tid = threadIdx.x;
    if (tid < 192) {
        int rr = tid / 24, jj = tid - rr * 24;
        Ds[rr][jj] = (jj < 12) ? Dre[(t0 + rr) * 12 + jj] : Dim[(t0 + rr) * 12 + jj - 12];
    }
    __syncthreads();
    for (int rep = 0; rep < 8; rep++) {
        int io = rep * 256 + tid;
        const float4* kp = (const float4*)(ker + io * 12);
        float4 ka = kp[0], kb = kp[1], kc = kp[2];
        float kv[12] = {ka.x, ka.y, ka.z, ka.w, kb.x, kb.y, kb.z, kb.w,
                        kc.x, kc.y, kc.z, kc.w};
#pragma unroll
        for (int rr = 0; rr < 8; rr++) {
            float sr = 0.f, si = 0.f;
#pragma unroll
            for (int j = 0; j < 12; j++) {
                sr += Ds[rr][j]      * kv[j];
                si += Ds[rr][12 + j] * kv[j];
            }
            yhb[(size_t)(t0 + rr) * 2048 + io] = pack2bf(sr, si);
        }
    }
}

// ---------------------------------------------------------------------------
// Fused beta-contraction + bf16 A-fragment pack. Xfb is Hermitian-half:
// rows ma 0..15 stored; ma>=17 read as conj(Xf[32-ma][(32-ng)&31]).
// Grid: (ma 32) x (zig 64) = 2048 blocks; thread = (zil 2, lq 4, ng 32).
// R9: b-loop grouped in beta-quads; wfT[bq][t][4] gives one float4 per
// (bq, l) instead of 4 scalar strided loads.
// ---------------------------------------------------------------------------
__global__ __launch_bounds__(256) void k_beta_A(const u32* __restrict__ Xfb,
                                                const float* __restrict__ wfT,
                                                u16* __restrict__ Ab) {
    int ma  = blockIdx.x >> 6;
    int zig = blockIdx.x & 63;
    int tid = threadIdx.x;
    int ng  = tid & 31;
    int lq  = (tid >> 5) & 3;
    int zil = tid >> 7;
    int zi  = zig * 2 + zil;
    int z = zi >> 5, i = zi & 31;
    int mh = (ma <= 15) ? ma : ma - 32;
    int nh = (ng <= 15) ? ng : ng - 32;
    int am = mh < 0 ? -mh : mh;
    int an = nh < 0 ? -nh : nh;
    int l0 = am > an ? am : an;
    int lb = lq * 4;

    int isconj = (ma > 16);
    int mau = isconj ? (32 - ma) : ma;
    int ngu = isconj ? ((32 - ng) & 31) : ng;
    if (mau > 15) { mau = 0; ngu = 0; }   // ma==16: l0==16, values unused

    int tl[4];
#pragma unroll
    for (int j = 0; j < 4; j++) {
        int l = lb + j;
        tl[j] = LB[l] + (mh + l) * (2 * l + 1) + (nh + l);
    }
    float2 acc[4];
#pragma unroll
    for (int j = 0; j < 4; j++) acc[j] = make_float2(0.f, 0.f);

    const u32* xp = Xfb + (size_t)zi * 32 * 512 + mau * 32 + ngu;
    float sgn = isconj ? -1.f : 1.f;
#pragma unroll 2
    for (int bq = 0; bq < 8; bq++) {
        u32 p0 = xp[(size_t)(4 * bq + 0) * 512];
        u32 p1 = xp[(size_t)(4 * bq + 1) * 512];
        u32 p2 = xp[(size_t)(4 * bq + 2) * 512];
        u32 p3 = xp[(size_t)(4 * bq + 3) * 512];
        float vx0 = __uint_as_float(p0 << 16);
        float vy0 = sgn * __uint_as_float(p0 & 0xffff0000u);
        float vx1 = __uint_as_float(p1 << 16);
        float vy1 = sgn * __uint_as_float(p1 & 0xffff0000u);
        float vx2 = __uint_as_float(p2 << 16);
        float vy2 = sgn * __uint_as_float(p2 & 0xffff0000u);
        float vx3 = __uint_as_float(p3 << 16);
        float vy3 = sgn * __uint_as_float(p3 & 0xffff0000u);
        const float4* wq = (const float4*)(wfT + (size_t)bq * (LTOT * 4));
#pragma unroll
        for (int j = 0; j < 4; j++) {
            if (lb + j >= l0) {
                float4 w = wq[tl[j]];
                acc[j].x += w.x * vx0 + w.y * vx1 + w.z * vx2 + w.w * vx3;
                acc[j].y += w.x * vy0 + w.y * vy1 + w.z * vy2 + w.w * vy3;
            }
        }
    }
    int s_i  = i >> 4;
    int kl   = 2 * (i & 15);
    int joff = kl & 7;
    int Lhi  = (kl >> 3) << 4;
#pragma unroll
    for (int j = 0; j < 4; j++) {
        int l = lb + j;
        if (l >= l0) {
            int mi = mh + l, ni = nh + l;
            int s   = 2 * ni + s_i;
            int row = 4 * mi + z;
            u32 pack = pack2bf(acc[j].x, acc[j].y);
            size_t off = (size_t)8192 * l * l + (size_t)s * 4096
                       + ((row >> 4) << 9) + ((Lhi + (row & 15)) << 3) + joff;
            *(u32*)(Ab + off) = pack;
        }
    }
}

// ---------------------------------------------------------------------------
// MFMA GEMM. 512 blocks = sum_l 2*(2l+1), big l first: block = (l, n, oh).
// R11: A read direct from global (the old As staging was an identity
// permutation); Bs double-buffered; next-iter A/B loads issued right after
// the single per-iter barrier so L2 latency hides under pack+MFMA.
// Cross-iter safety: R(s) of Bs[cur] precedes barrier(s+1) in program order
// (compiler drains lgkmcnt before s_barrier); W(s+2) to the same buffer
// happens after barrier(s+1) in all waves.
// Output transposed: zh_T[zo][t] (float pairs).
// ---------------------------------------------------------------------------
__global__ __launch_bounds__(256) void k_gemm(const u16* __restrict__ Ab,
                                              const u32* __restrict__ yhb,
                                              float* __restrict__ zhT) {
    __shared__ __align__(16) u16 Bs[2][2048];

    int rem = blockIdx.x, l, nl = 1;
    for (l = 15; l >= 0; l--) {
        nl = 2 * l + 1;
        int c = nl * 2;
        if (rem < c) break;
        rem -= c;
    }
    int n  = rem >> 1;
    int oh = rem & 1;
    int base = LB[l];
    const u16* Ag = Ab + (size_t)8192 * l * l;
    int S = 2 * nl;

    int tid = threadIdx.x, lane = tid & 63, w = tid >> 6;

    int kh = (tid >> 4) & 3;
    int nu = ((tid >> 6) << 4) + (tid & 15);
    int oo = (oh << 5) + (nu >> 1);
    int cc = nu & 1;

    // y base folds in n-row and kh/oo offsets; per s add k*nl*2048 + ih*1024
    const u32* ybase = yhb + (size_t)(base + n) * 2048 + (kh << 8) + oo;
    const u16* Aw = Ag + ((w << 10) | (lane << 3));

    floatx4 acc[2][4];
#pragma unroll
    for (int a = 0; a < 2; a++)
#pragma unroll
        for (int b = 0; b < 4; b++) acc[a][b] = (floatx4)0.f;

    u32 p0, p1, p2, p3;
    short8 a0r, a1r;
    {   // prologue: loads for s = 0 (k=0, ih=0)
        u32 b0 = ybase[0], b1 = ybase[64], b2 = ybase[128], b3 = ybase[192];
        if (cc == 0) {
            p0 = (b0 & 0xffffu) | ((b0 >> 16) << 16 ^ 0x80000000u);
            p1 = (b1 & 0xffffu) | ((b1 >> 16) << 16 ^ 0x80000000u);
            p2 = (b2 & 0xffffu) | ((b2 >> 16) << 16 ^ 0x80000000u);
            p3 = (b3 & 0xffffu) | ((b3 >> 16) << 16 ^ 0x80000000u);
        } else {
            p0 = (b0 >> 16) | (b0 << 16);
            p1 = (b1 >> 16) | (b1 << 16);
            p2 = (b2 >> 16) | (b2 << 16);
            p3 = (b3 >> 16) | (b3 << 16);
        }
        a0r = *(const short8*)(Aw);
        a1r = *(const short8*)(Aw + 512);
    }

    for (int s = 0; s < S; s++) {
        int cur = s & 1;
        *(uint4*)&Bs[cur][tid << 3] = make_uint4(p0, p1, p2, p3);
        short8 af0 = a0r, af1 = a1r;
        __syncthreads();
        if (s + 1 < S) {   // prefetch next step; consumed next iteration
            int sn = s + 1;
            int k = sn >> 1, ih = sn & 1;
            const u32* yr = ybase + (size_t)k * nl * 2048 + (ih << 10);
            u32 b0 = yr[0], b1 = yr[64], b2 = yr[128], b3 = yr[192];
            if (cc == 0) {
                p0 = (b0 & 0xffffu) | ((b0 >> 16) << 16 ^ 0x80000000u);
                p1 = (b1 & 0xffffu) | ((b1 >> 16) << 16 ^ 0x80000000u);
                p2 = (b2 & 0xffffu) | ((b2 >> 16) << 16 ^ 0x80000000u);
                p3 = (b3 & 0xffffu) | ((b3 >> 16) << 16 ^ 0x80000000u);
            } else {
                p0 = (b0 >> 16) | (b0 << 16);
                p1 = (b1 >> 16) | (b1 << 16);
                p2 = (b2 >> 16) | (b2 << 16);
                p3 = (b3 >> 16) | (b3 << 16);
            }
            a0r = *(const short8*)(Aw + (size_t)sn * 4096);
            a1r = *(const short8*)(Aw + (size_t)sn * 4096 + 512);
        }
#pragma unroll
        for (int nt = 0; nt < 4; nt++) {
            short8 bf = *(const short8*)&Bs[cur][nt * 512 + (lane << 3)];
            acc[0][nt] = __builtin_amdgcn_mfma_f32_16x16x32_bf16(af0, bf, acc[0][nt], 0, 0, 0);
            acc[1][nt] = __builtin_amdgcn_mfma_f32_16x16x32_bf16(af1, bf, acc[1][nt], 0, 0, 0);
        }
    }

    int q = lane >> 4, cn = lane & 15;
#pragma unroll
    for (int mt = 0; mt < 2; mt++) {
#pragma unroll
        for (int nt = 0; nt < 4; nt++) {
            int nu2 = (nt << 4) + cn;
            int o2  = (oh << 5) + (nu2 >> 1);
            int c2  = nu2 & 1;
#pragma unroll
            for (int r = 0; r < 4; r++) {
                int R = (w << 5) + (mt << 4) + (q << 2) + r;
                int m = R >> 2, z = R & 3;
                if (m < nl) {
                    int t  = base + m * nl + n;
                    int zo = (z << 6) + o2;
                    zhT[((size_t)zo * LTOT + t) * 2 + c2] = acc[mt][nt][r];
                }
            }
        }
    }
}

// ---------------------------------------------------------------------------
// Inverse, 4 betas per block: shared zv loads across betas, direct pass-2
// global write. R9: wiT[bq][t][4] -> one float4 per (l,t).
// R10: streamed FFT passes (no row[32]/col[16] staging) -> VGPR <=64,
// __launch_bounds__(256,8) -> 8 blocks/CU. bq-major block map: the 8 blocks
// sharing one zhT row have ids zo+256*bq == zo (mod 8) -> same XCD L2.
// Grid: 2048 = (bq 8) x (zo 256); 256 threads; LDS ~17 KB.
// ---------------------------------------------------------------------------
__global__ __launch_bounds__(256, 8) void k_inv2(const float2* __restrict__ zhT,
                                                 const float* __restrict__ wiT,
                                                 const float* __restrict__ bias,
                                                 float* __restrict__ out) {
    __shared__ float2 Pb[4 * 528];   // plane p at p*528, rows ma 0..15 stride 33
    __shared__ float Wc[32], Ws[32];
    int tid = threadIdx.x;
    int zo = blockIdx.x & 255;
    int bq = blockIdx.x >> 8;
    int b0 = bq * 4;
    if (tid < 32) {
        float sv, cv;
        sincosf(6.28318530717958647692f * (float)tid / 32.0f, &sv, &cv);
        Wc[tid] = cv; Ws[tid] = sv;
    }
    // ---- gather: thread = (ng 32, rq 8); 2 ma-rows; 4 betas share each zv
    {
        int ng = tid & 31, rq = tid >> 5;
        int nh = (ng <= 15) ? ng : ng - 32;
        int an = nh < 0 ? -nh : nh;
        const float2* zr = zhT + (size_t)zo * LTOT;
        const float4* wp = (const float4*)(wiT + (size_t)bq * (LTOT * 4));
#pragma unroll
        for (int mr = 0; mr < 2; mr++) {
            int ma = rq + 8 * mr;
            int l0 = ma > an ? ma : an;
            float2 a0 = make_float2(0.f, 0.f), a1 = a0, a2 = a0, a3 = a0;
#pragma unroll 4
            for (int l = 0; l < 16; l++) {
                if (l >= l0) {
                    int t = LB[l] + (ma + l) * (2 * l + 1) + (nh + l);
                    float2 zv = zr[t];
                    float4 w = wp[t];
                    a0.x += w.x * zv.x; a0.y += w.x * zv.y;
                    a1.x += w.y * zv.x; a1.y += w.y * zv.y;
                    a2.x += w.z * zv.x; a2.y += w.z * zv.y;
                    a3.x += w.w * zv.x; a3.y += w.w * zv.y;
                }
            }
            int po = ma * 33 + ng;
            Pb[po]            = a0;
            Pb[528 + po]      = a1;
            Pb[2 * 528 + po]  = a2;
            Pb[3 * 528 + po]  = a3;
        }
    }
    __syncthreads();
    // ---- pass 1 (ng -> g), radix-2, in-place: 64 rows x 8 thr = 512 tasks.
    // Streamed: read each LDS value once, accumulate E/O for k and k+8.
    // Row-sharing threads are one wave (lockstep); reads precede writes in
    // program order, so in-place update stays race-free.
#pragma unroll
    for (int it = 0; it < 2; it++) {
        int task = tid + it * 256;
        int rowid = task >> 3, q = task & 7;
        float2* prow = &Pb[(rowid >> 4) * 528 + (rowid & 15) * 33];
        float2 E0 = make_float2(0.f, 0.f), O0 = E0, E1 = E0, O1 = E0;
        int k1 = q + 8;
#pragma unroll 4
        for (int h = 0; h < 16; h++) {
            float2 e = prow[2 * h], o = prow[2 * h + 1];
            int i0 = (2 * h * q) & 31;
            int i1 = (2 * h * k1) & 31;
            float c0 = Wc[i0], s0 = Ws[i0];
            float c1 = Wc[i1], s1 = Ws[i1];
            E0.x += e.x * c0 - e.y * s0;  E0.y += e.x * s0 + e.y * c0;
            O0.x += o.x * c0 - o.y * s0;  O0.y += o.x * s0 + o.y * c0;
            E1.x += e.x * c1 - e.y * s1;  E1.y += e.x * s1 + e.y * c1;
            O1.x += o.x * c1 - o.y * s1;  O1.y += o.x * s1 + o.y * c1;
        }
        float c0 = Wc[q],  s0 = Ws[q];
        float c1 = Wc[k1], s1 = Ws[k1];
        float2 w0 = make_float2(O0.x * c0 - O0.y * s0, O0.x * s0 + O0.y * c0);
        float2 w1 = make_float2(O1.x * c1 - O1.y * s1, O1.x * s1 + O1.y * c1);
        prow[q]      = make_float2(E0.x + w0.x, E0.y + w0.y);
        prow[q + 16] = make_float2(E0.x - w0.x, E0.y - w0.y);
        prow[q + 8]  = make_float2(E1.x + w1.x, E1.y + w1.y);
        prow[q + 24] = make_float2(E1.x - w1.x, E1.y - w1.y);
    }
    __syncthreads();
    // ---- pass 2 (ma -> a): streamed even/odd column reads, direct store
    float bv = bias[zo & 63];
#pragma unroll
    for (int it = 0; it < 2; it++) {
        int task = tid + it * 256;
        int p = task >> 7, rr = task & 127;
        int qa = rr >> 5, g = rr & 31;
        const float2* pc = &Pb[p * 528];
        float2 c0 = pc[g];
        float Ea[4], Oa[4];
#pragma unroll
        for (int jj = 0; jj < 4; jj++) { Ea[jj] = c0.x; Oa[jj] = 0.f; }
#pragma unroll 4
        for (int j = 1; j < 8; j++) {
            float2 c = pc[(2 * j) * 33 + g];
#pragma unroll
            for (int jj = 0; jj < 4; jj++) {
                int a = qa * 4 + jj;
                int idx = ((2 * j) * a) & 31;
                Ea[jj] += 2.f * (c.x * Wc[idx] - c.y * Ws[idx]);
            }
        }
#pragma unroll 4
        for (int j = 0; j < 8; j++) {
            float2 c = pc[(2 * j + 1) * 33 + g];
#pragma unroll
            for (int jj = 0; jj < 4; jj++) {
                int a = qa * 4 + jj;
                int idx = ((2 * j + 1) * a) & 31;
                Oa[jj] += 2.f * (c.x * Wc[idx] - c.y * Ws[idx]);
            }
        }
        float* dst = out + (size_t)zo * 32768 + (size_t)(b0 + p) * 1024;
#pragma unroll
        for (int jj = 0; jj < 4; jj++) {
            int a = qa * 4 + jj;
            dst[a * 32 + g]        = (Ea[jj] + Oa[jj]) * (1.f / 1024.f) + bv;
            dst[(a + 16) * 32 + g] = (Ea[jj] - Oa[jj]) * (1.f / 1024.f) + bv;
        }
    }
}

// ---------------------------------------------------------------------------
extern "C" void kernel_launch(void* const* d_in, const int* in_sizes, int n_in,
                              void* d_out, int out_size, void* d_ws, size_t ws_size,
                              hipStream_t stream) {
    const float* x    = (const float*)d_in[0];
    const float* ker  = (const float*)d_in[1];
    const float* bias = (const float*)d_in[2];
    const float* wf   = (const float*)d_in[3];
    const float* wi   = (const float*)d_in[4];
    const float* Dre  = (const float*)d_in[5];
    const float* Dim  = (const float*)d_in[6];
    float* out = (float*)d_out;

    // layout: yhb 44.7MB | Ab 4.2MB | zh_T 11.2MB.
    // Xfb (8.4MB) + wfT (698KB, at zhT+8.39MB) alias zh_T: both dead once
    // k_gemm writes zhT. wiT (698KB) aliases yhb base: written after k_gemm
    // (yhb dead), read by k_inv2.
    char* ws = (char*)d_ws;
    u32*    yhb = (u32*)ws;
    u16*    Ab  = (u16*)(ws + 44695552);
    float*  zhT = (float*)(ws + 44695552 + 4194304);
    u32*    Xfb = (u32*)zhT;                                    // disjoint lifetime vs zh_T
    float*  wfT = (float*)(ws + 44695552 + 4194304 + 8388608);  // zhT tail, pre-gemm
    float*  wiT = (float*)ws;                                   // yhb region, post-gemm

    hipLaunchKernelGGL(k_fft_fwd, dim3(4096),  dim3(512), 0, stream, x, Xfb);
    hipLaunchKernelGGL(k_wtr,     dim3(22, 8), dim3(256), 0, stream, wf, wfT);
    hipLaunchKernelGGL(k_prep_B,  dim3(682),   dim3(256), 0, stream, Dre, Dim, ker, yhb);
    hipLaunchKernelGGL(k_beta_A,  dim3(2048),  dim3(256), 0, stream, Xfb, wfT, Ab);
    hipLaunchKernelGGL(k_gemm,    dim3(512),   dim3(256), 0, stream, Ab, yhb, zhT);
    hipLaunchKernelGGL(k_wtr,     dim3(22, 8), dim3(256), 0, stream, wi, wiT);
    hipLaunchKernelGGL(k_inv2,    dim3(2048),  dim3(256), 0, stream,
                       (const float2*)zhT, wiT, bias, out);
}

// Round 4
// 224.281 us; speedup vs baseline: 1.0708x; 1.0708x over previous
//
#include <hip/hip_runtime.h>
#include <math.h>

// ---------------------------------------------------------------------------
// SO3 convolution. bf16 MFMA GEMM (complex-as-real); Hermitian-half FFT/IFFT.
// Pipeline: k_fft_fwd (Hermitian bf16 out) -> k_wtr(wf) -> k_prep_B
//           -> k_beta_A -> k_gemm (MFMA) -> k_wtr(wi) -> k_inv2
// R8 lesson: fusing fft+prep spilled -- keep kernels separate.
// R9: wfT/wiT [bq][t][4] transposes -- big win in k_beta_A.
// R10: k_inv2 streamed FFT passes (VGPR 92->64), 8 blocks/CU -- 68->~40us.
// R11 NEUTRAL: barrier/staging removal + depth-1 prefetch didn't move k_gemm
// -- it's latency-bound with ~150cy cover vs ~600-900cy yhb (L3) latency,
// and grid=512 (2 blocks/CU) gives no TLP.
// R12: yhb stored in MFMA-FRAGMENT ORDER (prep_B writes permuted index, same
// size) so B-fragments are contiguous uint4 global loads; cc-transform done
// per-lane (v_perm + xor, 2 VALU/word). k_gemm has NO LDS and NO barriers;
// 2-deep named-register pipeline; compiler free to schedule across steps.
// Workspace: yhb 44.7MB | Ab 4.2MB | zh_T 11.2MB.
//   Xfb (8.4MB) + wfT (698KB) alias zh_T (lifetime fft->gemm, disjoint).
//   wiT (698KB) aliases yhb base (written after gemm, read by inv2).
// ---------------------------------------------------------------------------

typedef unsigned short u16;
typedef unsigned int   u32;
typedef __attribute__((ext_vector_type(8))) short  short8;   // 8 bf16
typedef __attribute__((ext_vector_type(4))) float  floatx4;

constexpr int LTOT = 5456;

constexpr int LB[17] = {0,1,10,35,84,165,286,455,680,969,
                        1330,1771,2300,2925,3654,4495,5456};

__device__ inline u16 f2bf(float f) {
    u32 u = __float_as_uint(f);
    u += 0x7fff + ((u >> 16) & 1);
    return (u16)(u >> 16);
}
__device__ inline u32 pack2bf(float re, float im) {
    return (u32)f2bf(re) | ((u32)f2bf(im) << 16);
}

// cc-dependent complex pack transform: cc=0 -> (re,-im) == b ^ 0x80000000;
// cc=1 -> (im,re) == ror16(b). Done as per-lane-constant perm + xor.
__device__ inline short8 btr4(uint4 q, u32 sel, u32 msk) {
    uint4 t;
    t.x = __builtin_amdgcn_perm(q.x, q.x, sel) ^ msk;
    t.y = __builtin_amdgcn_perm(q.y, q.y, sel) ^ msk;
    t.z = __builtin_amdgcn_perm(q.z, q.z, sel) ^ msk;
    t.w = __builtin_amdgcn_perm(q.w, q.w, sel) ^ msk;
    return *(short8*)&t;
}

// ---------------------------------------------------------------------------
// Wigner-table transpose: w[32][LTOT] -> wT[bq(8)][t][4] so a 4-beta group is
// one float4. Grid (22, 8) x 256.
// ---------------------------------------------------------------------------
__global__ __launch_bounds__(256) void k_wtr(const float* __restrict__ w,
                                             float* __restrict__ wT) {
    int t  = blockIdx.x * 256 + threadIdx.x;
    int bq = blockIdx.y;
    if (t < LTOT) {
        float4 v;
        v.x = w[(size_t)(bq * 4 + 0) * LTOT + t];
        v.y = w[(size_t)(bq * 4 + 1) * LTOT + t];
        v.z = w[(size_t)(bq * 4 + 2) * LTOT + t];
        v.w = w[(size_t)(bq * 4 + 3) * LTOT + t];
        *(float4*)(wT + ((size_t)bq * LTOT + t) * 4) = v;
    }
}

// ---------------------------------------------------------------------------
// Forward FFT2 (e^{-i}), radix-2 both passes, 512 threads, one task each.
// Stores ONLY Hermitian-half rows ma 0..15, bf16-packed.
// x: [z][i][b][a][g].   Xfb: [zi*32+b][ma(0..15)][ng] packed bf16 pairs.
// ---------------------------------------------------------------------------
__global__ __launch_bounds__(512) void k_fft_fwd(const float* __restrict__ x,
                                                 u32* __restrict__ Xfb) {
    __shared__ float xs[1056];               // [a][g] stride 33
    __shared__ float Gre[1056], Gim[1056];   // [a][k] stride 33
    __shared__ float Wc[32], Ws[32];
    int tid = threadIdx.x;
    if (tid < 32) {
        float sv, cv;
        sincosf(6.28318530717958647692f * (float)tid / 32.0f, &sv, &cv);
        Wc[tid] = cv; Ws[tid] = sv;
    }
    const float* src = x + (size_t)blockIdx.x * 1024;
    for (int e = tid; e < 1024; e += 512) xs[(e >> 5) * 33 + (e & 31)] = src[e];
    __syncthreads();
    // pass 1 over g (real input), radix-2: task = (a, k in 0..15)
    {
        int a = tid >> 4, k = tid & 15;
        const float* row = &xs[a * 33];
        float Er = 0.f, Ei = 0.f, Or = 0.f, Oi = 0.f;
#pragma unroll
        for (int h = 0; h < 16; h++) {
            int idx = (2 * h * k) & 31;
            float c = Wc[idx], s = Ws[idx];
            float xe = row[2 * h], xo = row[2 * h + 1];
            Er += xe * c;  Ei -= xe * s;
            Or += xo * c;  Oi -= xo * s;
        }
        float WOr = Or * Wc[k] + Oi * Ws[k];
        float WOi = Oi * Wc[k] - Or * Ws[k];
        Gre[a * 33 + k]      = Er + WOr;
        Gim[a * 33 + k]      = Ei + WOi;
        Gre[a * 33 + k + 16] = Er - WOr;
        Gim[a * 33 + k + 16] = Ei - WOi;
    }
    __syncthreads();
    // pass 2 over a, radix-2 combine; store only row ma (0..15)
    {
        u32* dst = Xfb + (size_t)blockIdx.x * 512;
        int ng = tid & 31, ma = tid >> 5;
        float Er = 0.f, Ei = 0.f, Or = 0.f, Oi = 0.f;
#pragma unroll
        for (int h = 0; h < 16; h++) {
            int idx = (2 * h * ma) & 31;
            float c = Wc[idx], s = Ws[idx];
            float er = Gre[(2 * h) * 33 + ng],      ei = Gim[(2 * h) * 33 + ng];
            float orr = Gre[(2 * h + 1) * 33 + ng], oi = Gim[(2 * h + 1) * 33 + ng];
            Er += er * c + ei * s;   Ei += ei * c - er * s;
            Or += orr * c + oi * s;  Oi += oi * c - orr * s;
        }
        float WOr = Or * Wc[ma] + Oi * Ws[ma];
        float WOi = Oi * Wc[ma] - Or * Ws[ma];
        dst[ma * 32 + ng] = pack2bf(Er + WOr, Ei + WOi);
    }
}

// ---------------------------------------------------------------------------
// Build compact bf16 yh in MFMA-FRAGMENT ORDER (R12):
// io = (i,o): i = ih*16+kh*4+j, o = oh*32+nt*8+ph
// nio = ih*1024 + oh*512 + nt*128 + kh*32 + ph*4 + j
// so k_gemm's lane fragment (4 words j=0..3) is one contiguous uint4.
// ---------------------------------------------------------------------------
__global__ __launch_bounds__(256) void k_prep_B(const float* __restrict__ Dre,
                                                const float* __restrict__ Dim,
                                                const float* __restrict__ ker,
                                                u32* __restrict__ yhb) {
    __shared__ float Ds[8][24];
    int t0  = blockIdx.x * 8;
    int tid = threadIdx.x;
    if (tid < 192) {
        int rr = tid / 24, jj = tid - rr * 24;
        Ds[rr][jj] = (jj < 12) ? Dre[(t0 + rr) * 12 + jj] : Dim[(t0 + rr) * 12 + jj - 12];
    }
    __syncthreads();
    for (int rep = 0; rep < 8; rep++) {
        int io = rep * 256 + tid;
        int i  = io >> 6, o = io & 63;
        int nio = ((i >> 4) << 10) + ((o >> 5) << 9) + (((o >> 3) & 3) << 7)
                + (((i >> 2) & 3) << 5) + ((o & 7) << 2) + (i & 3);
        const float4* kp = (const float4*)(ker + io * 12);
        float4 ka = kp[0], kb = kp[1], kc = kp[2];
        float kv[12] = {ka.x, ka.y, ka.z, ka.w, kb.x, kb.y, kb.z, kb.w,
                        kc.x, kc.y, kc.z, kc.w};
#pragma unroll
        for (int rr = 0; rr < 8; rr++) {
            float sr = 0.f, si = 0.f;
#pragma unroll
            for (int j = 0; j < 12; j++) {
                sr += Ds[rr][j]      * kv[j];
                si += Ds[rr][12 + j] * kv[j];
            }
            yhb[(size_t)(t0 + rr) * 2048 + nio] = pack2bf(sr, si);
        }
    }
}

// ---------------------------------------------------------------------------
// Fused beta-contraction + bf16 A-fragment pack. Xfb is Hermitian-half:
// rows ma 0..15 stored; ma>=17 read as conj(Xf[32-ma][(32-ng)&31]).
// Grid: (ma 32) x (zig 64) = 2048 blocks; thread = (zil 2, lq 4, ng 32).
// R9: b-loop grouped in beta-quads; wfT[bq][t][4] gives one float4 per
// (bq, l) instead of 4 scalar strided loads.
// ---------------------------------------------------------------------------
__global__ __launch_bounds__(256) void k_beta_A(const u32* __restrict__ Xfb,
                                                const float* __restrict__ wfT,
                                                u16* __restrict__ Ab) {
    int ma  = blockIdx.x >> 6;
    int zig = blockIdx.x & 63;
    int tid = threadIdx.x;
    int ng  = tid & 31;
    int lq  = (tid >> 5) & 3;
    int zil = tid >> 7;
    int zi  = zig * 2 + zil;
    int z = zi >> 5, i = zi & 31;
    int mh = (ma <= 15) ? ma : ma - 32;
    int nh = (ng <= 15) ? ng : ng - 32;
    int am = mh < 0 ? -mh : mh;
    int an = nh < 0 ? -nh : nh;
    int l0 = am > an ? am : an;
    int lb = lq * 4;

    int isconj = (ma > 16);
    int mau = isconj ? (32 - ma) : ma;
    int ngu = isconj ? ((32 - ng) & 31) : ng;
    if (mau > 15) { mau = 0; ngu = 0; }   // ma==16: l0==16, values unused

    int tl[4];
#pragma unroll
    for (int j = 0; j < 4; j++) {
        int l = lb + j;
        tl[j] = LB[l] + (mh + l) * (2 * l + 1) + (nh + l);
    }
    float2 acc[4];
#pragma unroll
    for (int j = 0; j < 4; j++) acc[j] = make_float2(0.f, 0.f);

    const u32* xp = Xfb + (size_t)zi * 32 * 512 + mau * 32 + ngu;
    float sgn = isconj ? -1.f : 1.f;
#pragma unroll 2
    for (int bq = 0; bq < 8; bq++) {
        u32 p0 = xp[(size_t)(4 * bq + 0) * 512];
        u32 p1 = xp[(size_t)(4 * bq + 1) * 512];
        u32 p2 = xp[(size_t)(4 * bq + 2) * 512];
        u32 p3 = xp[(size_t)(4 * bq + 3) * 512];
        float vx0 = __uint_as_float(p0 << 16);
        float vy0 = sgn * __uint_as_float(p0 & 0xffff0000u);
        float vx1 = __uint_as_float(p1 << 16);
        float vy1 = sgn * __uint_as_float(p1 & 0xffff0000u);
        float vx2 = __uint_as_float(p2 << 16);
        float vy2 = sgn * __uint_as_float(p2 & 0xffff0000u);
        float vx3 = __uint_as_float(p3 << 16);
        float vy3 = sgn * __uint_as_float(p3 & 0xffff0000u);
        const float4* wq = (const float4*)(wfT + (size_t)bq * (LTOT * 4));
#pragma unroll
        for (int j = 0; j < 4; j++) {
            if (lb + j >= l0) {
                float4 w = wq[tl[j]];
                acc[j].x += w.x * vx0 + w.y * vx1 + w.z * vx2 + w.w * vx3;
                acc[j].y += w.x * vy0 + w.y * vy1 + w.z * vy2 + w.w * vy3;
            }
        }
    }
    int s_i  = i >> 4;
    int kl   = 2 * (i & 15);
    int joff = kl & 7;
    int Lhi  = (kl >> 3) << 4;
#pragma unroll
    for (int j = 0; j < 4; j++) {
        int l = lb + j;
        if (l >= l0) {
            int mi = mh + l, ni = nh + l;
            int s   = 2 * ni + s_i;
            int row = 4 * mi + z;
            u32 pack = pack2bf(acc[j].x, acc[j].y);
            size_t off = (size_t)8192 * l * l + (size_t)s * 4096
                       + ((row >> 4) << 9) + ((Lhi + (row & 15)) << 3) + joff;
            *(u32*)(Ab + off) = pack;
        }
    }
}

// ---------------------------------------------------------------------------
// MFMA GEMM, R12: NO LDS, NO barriers. B-fragments read as contiguous uint4
// from fragment-ordered yhb (even/odd lanes share an address -> coalesced);
// per-lane perm+xor does the complex pack. A direct short8. 2-deep named-
// register pipeline; waves fully independent.
// 512 blocks = sum_l 2*(2l+1), big l first: block = (l, n, oh).
// Output transposed: zh_T[zo][t] (float pairs).
// ---------------------------------------------------------------------------
__global__ __launch_bounds__(256) void k_gemm(const u16* __restrict__ Ab,
                                              const u32* __restrict__ yhb,
                                              float* __restrict__ zhT) {
    int rem = blockIdx.x, l, nl = 1;
    for (l = 15; l >= 0; l--) {
        nl = 2 * l + 1;
        int c = nl * 2;
        if (rem < c) break;
        rem -= c;
    }
    int n  = rem >> 1;
    int oh = rem & 1;
    int base = LB[l];
    const u16* Ag = Ab + (size_t)8192 * l * l;
    int S = 2 * nl;

    int tid = threadIdx.x, lane = tid & 63, w = tid >> 6;
    int cc = lane & 1;
    u32 sel = cc ? 0x01000302u : 0x03020100u;   // ror16 : identity
    u32 msk = cc ? 0u          : 0x80000000u;   // 0     : negate-hi

    // B: per step s=(k,ih): uint4 at yhb32 + (base+k*nl+n)*2048 + ih*1024
    //    + oh*512 + (lane>>1)*4, nt-stride 128 u32 (32 uint4).
    const u32* Bb = yhb + (size_t)(base + n) * 2048 + (oh << 9) + ((lane >> 1) << 2);
    const u16* Aw = Ag + ((w << 10) | (lane << 3));

    floatx4 acc[2][4];
#pragma unroll
    for (int a = 0; a < 2; a++)
#pragma unroll
        for (int b = 0; b < 4; b++) acc[a][b] = (floatx4)0.f;

#define LOADB(s, q0, q1, q2, q3) { \
    const uint4* bp = (const uint4*)(Bb + (size_t)((s) >> 1) * nl * 2048 + (((s) & 1) << 10)); \
    q0 = bp[0]; q1 = bp[32]; q2 = bp[64]; q3 = bp[96]; }
#define LOADA(s, r0, r1) { \
    const u16* apx = Aw + (size_t)(s) * 4096; \
    r0 = *(const short8*)apx; r1 = *(const short8*)(apx + 512); }
#define MF(a, b, c) __builtin_amdgcn_mfma_f32_16x16x32_bf16(a, b, c, 0, 0, 0)

    uint4 eB0, eB1, eB2, eB3; short8 ea0, ea1;   // even-step raw
    uint4 oB0, oB1, oB2, oB3; short8 oa0, oa1;   // odd-step raw
    LOADA(0, ea0, ea1); LOADB(0, eB0, eB1, eB2, eB3);
    LOADA(1, oa0, oa1); LOADB(1, oB0, oB1, oB2, oB3);

    for (int s = 0; s < S; s += 2) {
        // even step: transform (waits on its loads), refill regs, then MFMA
        short8 bf0 = btr4(eB0, sel, msk), bf1 = btr4(eB1, sel, msk);
        short8 bf2 = btr4(eB2, sel, msk), bf3 = btr4(eB3, sel, msk);
        short8 af0 = ea0, af1 = ea1;
        if (s + 2 < S) { LOADA(s + 2, ea0, ea1); LOADB(s + 2, eB0, eB1, eB2, eB3); }
        acc[0][0] = MF(af0, bf0, acc[0][0]);  acc[1][0] = MF(af1, bf0, acc[1][0]);
        acc[0][1] = MF(af0, bf1, acc[0][1]);  acc[1][1] = MF(af1, bf1, acc[1][1]);
        acc[0][2] = MF(af0, bf2, acc[0][2]);  acc[1][2] = MF(af1, bf2, acc[1][2]);
        acc[0][3] = MF(af0, bf3, acc[0][3]);  acc[1][3] = MF(af1, bf3, acc[1][3]);
        // odd step
        short8 cf0 = btr4(oB0, sel, msk), cf1 = btr4(oB1, sel, msk);
        short8 cf2 = btr4(oB2, sel, msk), cf3 = btr4(oB3, sel, msk);
        short8 ag0 = oa0, ag1 = oa1;
        if (s + 3 < S) { LOADA(s + 3, oa0, oa1); LOADB(s + 3, oB0, oB1, oB2, oB3); }
        acc[0][0] = MF(ag0, cf0, acc[0][0]);  acc[1][0] = MF(ag1, cf0, acc[1][0]);
        acc[0][1] = MF(ag0, cf1, acc[0][1]);  acc[1][1] = MF(ag1, cf1, acc[1][1]);
        acc[0][2] = MF(ag0, cf2, acc[0][2]);  acc[1][2] = MF(ag1, cf2, acc[1][2]);
        acc[0][3] = MF(ag0, cf3, acc[0][3]);  acc[1][3] = MF(ag1, cf3, acc[1][3]);
    }
#undef LOADB
#undef LOADA
#undef MF

    int q = lane >> 4, cn = lane & 15;
#pragma unroll
    for (int mt = 0; mt < 2; mt++) {
#pragma unroll
        for (int nt = 0; nt < 4; nt++) {
            int nu2 = (nt << 4) + cn;
            int o2  = (oh << 5) + (nu2 >> 1);
            int c2  = nu2 & 1;
#pragma unroll
            for (int r = 0; r < 4; r++) {
                int R = (w << 5) + (mt << 4) + (q << 2) + r;
                int m = R >> 2, z = R & 3;
                if (m < nl) {
                    int t  = base + m * nl + n;
                    int zo = (z << 6) + o2;
                    zhT[((size_t)zo * LTOT + t) * 2 + c2] = acc[mt][nt][r];
                }
            }
        }
    }
}

// ---------------------------------------------------------------------------
// Inverse, 4 betas per block: shared zv loads across betas, direct pass-2
// global write. R9: wiT[bq][t][4] -> one float4 per (l,t).
// R10: streamed FFT passes (no row[32]/col[16] staging) -> VGPR <=64,
// __launch_bounds__(256,8) -> 8 blocks/CU. bq-major block map: the 8 blocks
// sharing one zhT row have ids zo+256*bq == zo (mod 8) -> same XCD L2.
// Grid: 2048 = (bq 8) x (zo 256); 256 threads; LDS ~17 KB.
// ---------------------------------------------------------------------------
__global__ __launch_bounds__(256, 8) void k_inv2(const float2* __restrict__ zhT,
                                                 const float* __restrict__ wiT,
                                                 const float* __restrict__ bias,
                                                 float* __restrict__ out) {
    __shared__ float2 Pb[4 * 528];   // plane p at p*528, rows ma 0..15 stride 33
    __shared__ float Wc[32], Ws[32];
    int tid = threadIdx.x;
    int zo = blockIdx.x & 255;
    int bq = blockIdx.x >> 8;
    int b0 = bq * 4;
    if (tid < 32) {
        float sv, cv;
        sincosf(6.28318530717958647692f * (float)tid / 32.0f, &sv, &cv);
        Wc[tid] = cv; Ws[tid] = sv;
    }
    // ---- gather: thread = (ng 32, rq 8); 2 ma-rows; 4 betas share each zv
    {
        int ng = tid & 31, rq = tid >> 5;
        int nh = (ng <= 15) ? ng : ng - 32;
        int an = nh < 0 ? -nh : nh;
        const float2* zr = zhT + (size_t)zo * LTOT;
        const float4* wp = (const float4*)(wiT + (size_t)bq * (LTOT * 4));
#pragma unroll
        for (int mr = 0; mr < 2; mr++) {
            int ma = rq + 8 * mr;
            int l0 = ma > an ? ma : an;
            float2 a0 = make_float2(0.f, 0.f), a1 = a0, a2 = a0, a3 = a0;
#pragma unroll 4
            for (int l = 0; l < 16; l++) {
                if (l >= l0) {
                    int t = LB[l] + (ma + l) * (2 * l + 1) + (nh + l);
                    float2 zv = zr[t];
                    float4 w = wp[t];
                    a0.x += w.x * zv.x; a0.y += w.x * zv.y;
                    a1.x += w.y * zv.x; a1.y += w.y * zv.y;
                    a2.x += w.z * zv.x; a2.y += w.z * zv.y;
                    a3.x += w.w * zv.x; a3.y += w.w * zv.y;
                }
            }
            int po = ma * 33 + ng;
            Pb[po]            = a0;
            Pb[528 + po]      = a1;
            Pb[2 * 528 + po]  = a2;
            Pb[3 * 528 + po]  = a3;
        }
    }
    __syncthreads();
    // ---- pass 1 (ng -> g), radix-2, in-place: 64 rows x 8 thr = 512 tasks.
    // Streamed: read each LDS value once, accumulate E/O for k and k+8.
    // Row-sharing threads are one wave (lockstep); reads precede writes in
    // program order, so in-place update stays race-free.
#pragma unroll
    for (int it = 0; it < 2; it++) {
        int task = tid + it * 256;
        int rowid = task >> 3, q = task & 7;
        float2* prow = &Pb[(rowid >> 4) * 528 + (rowid & 15) * 33];
        float2 E0 = make_float2(0.f, 0.f), O0 = E0, E1 = E0, O1 = E0;
        int k1 = q + 8;
#pragma unroll 4
        for (int h = 0; h < 16; h++) {
            float2 e = prow[2 * h], o = prow[2 * h + 1];
            int i0 = (2 * h * q) & 31;
            int i1 = (2 * h * k1) & 31;
            float c0 = Wc[i0], s0 = Ws[i0];
            float c1 = Wc[i1], s1 = Ws[i1];
            E0.x += e.x * c0 - e.y * s0;  E0.y += e.x * s0 + e.y * c0;
            O0.x += o.x * c0 - o.y * s0;  O0.y += o.x * s0 + o.y * c0;
            E1.x += e.x * c1 - e.y * s1;  E1.y += e.x * s1 + e.y * c1;
            O1.x += o.x * c1 - o.y * s1;  O1.y += o.x * s1 + o.y * c1;
        }
        float c0 = Wc[q],  s0 = Ws[q];
        float c1 = Wc[k1], s1 = Ws[k1];
        float2 w0 = make_float2(O0.x * c0 - O0.y * s0, O0.x * s0 + O0.y * c0);
        float2 w1 = make_float2(O1.x * c1 - O1.y * s1, O1.x * s1 + O1.y * c1);
        prow[q]      = make_float2(E0.x + w0.x, E0.y + w0.y);
        prow[q + 16] = make_float2(E0.x - w0.x, E0.y - w0.y);
        prow[q + 8]  = make_float2(E1.x + w1.x, E1.y + w1.y);
        prow[q + 24] = make_float2(E1.x - w1.x, E1.y - w1.y);
    }
    __syncthreads();
    // ---- pass 2 (ma -> a): streamed even/odd column reads, direct store
    float bv = bias[zo & 63];
#pragma unroll
    for (int it = 0; it < 2; it++) {
        int task = tid + it * 256;
        int p = task >> 7, rr = task & 127;
        int qa = rr >> 5, g = rr & 31;
        const float2* pc = &Pb[p * 528];
        float2 c0 = pc[g];
        float Ea[4], Oa[4];
#pragma unroll
        for (int jj = 0; jj < 4; jj++) { Ea[jj] = c0.x; Oa[jj] = 0.f; }
#pragma unroll 4
        for (int j = 1; j < 8; j++) {
            float2 c = pc[(2 * j) * 33 + g];
#pragma unroll
            for (int jj = 0; jj < 4; jj++) {
                int a = qa * 4 + jj;
                int idx = ((2 * j) * a) & 31;
                Ea[jj] += 2.f * (c.x * Wc[idx] - c.y * Ws[idx]);
            }
        }
#pragma unroll 4
        for (int j = 0; j < 8; j++) {
            float2 c = pc[(2 * j + 1) * 33 + g];
#pragma unroll
            for (int jj = 0; jj < 4; jj++) {
                int a = qa * 4 + jj;
                int idx = ((2 * j + 1) * a) & 31;
                Oa[jj] += 2.f * (c.x * Wc[idx] - c.y * Ws[idx]);
            }
        }
        float* dst = out + (size_t)zo * 32768 + (size_t)(b0 + p) * 1024;
#pragma unroll
        for (int jj = 0; jj < 4; jj++) {
            int a = qa * 4 + jj;
            dst[a * 32 + g]        = (Ea[jj] + Oa[jj]) * (1.f / 1024.f) + bv;
            dst[(a + 16) * 32 + g] = (Ea[jj] - Oa[jj]) * (1.f / 1024.f) + bv;
        }
    }
}

// ---------------------------------------------------------------------------
extern "C" void kernel_launch(void* const* d_in, const int* in_sizes, int n_in,
                              void* d_out, int out_size, void* d_ws, size_t ws_size,
                              hipStream_t stream) {
    const float* x    = (const float*)d_in[0];
    const float* ker  = (const float*)d_in[1];
    const float* bias = (const float*)d_in[2];
    const float* wf   = (const float*)d_in[3];
    const float* wi   = (const float*)d_in[4];
    const float* Dre  = (const float*)d_in[5];
    const float* Dim  = (const float*)d_in[6];
    float* out = (float*)d_out;

    // layout: yhb 44.7MB | Ab 4.2MB | zh_T 11.2MB.
    // Xfb (8.4MB) + wfT (698KB, at zhT+8.39MB) alias zh_T: both dead once
    // k_gemm writes zhT. wiT (698KB) aliases yhb base: written after k_gemm
    // (yhb dead), read by k_inv2.
    char* ws = (char*)d_ws;
    u32*    yhb = (u32*)ws;
    u16*    Ab  = (u16*)(ws + 44695552);
    float*  zhT = (float*)(ws + 44695552 + 4194304);
    u32*    Xfb = (u32*)zhT;                                    // disjoint lifetime vs zh_T
    float*  wfT = (float*)(ws + 44695552 + 4194304 + 8388608);  // zhT tail, pre-gemm
    float*  wiT = (float*)ws;                                   // yhb region, post-gemm

    hipLaunchKernelGGL(k_fft_fwd, dim3(4096),  dim3(512), 0, stream, x, Xfb);
    hipLaunchKernelGGL(k_wtr,     dim3(22, 8), dim3(256), 0, stream, wf, wfT);
    hipLaunchKernelGGL(k_prep_B,  dim3(682),   dim3(256), 0, stream, Dre, Dim, ker, yhb);
    hipLaunchKernelGGL(k_beta_A,  dim3(2048),  dim3(256), 0, stream, Xfb, wfT, Ab);
    hipLaunchKernelGGL(k_gemm,    dim3(512),   dim3(256), 0, stream, Ab, yhb, zhT);
    hipLaunchKernelGGL(k_wtr,     dim3(22, 8), dim3(256), 0, stream, wi, wiT);
    hipLaunchKernelGGL(k_inv2,    dim3(2048),  dim3(256), 0, stream,
                       (const float2*)zhT, wiT, bias, out);
}

// Round 5
// 221.346 us; speedup vs baseline: 1.0850x; 1.0133x over previous
//
#include <hip/hip_runtime.h>
#include <math.h>

// ---------------------------------------------------------------------------
// SO3 convolution. bf16 MFMA GEMM (complex-as-real); Hermitian-half FFT/IFFT.
// Pipeline: k_fft_fwd (Hermitian bf16 out) -> k_wtr(wf) -> k_prep_B
//           -> k_beta_A -> k_gemm (MFMA) -> k_wtr(wi) -> k_inv2
// R8 lesson: fusing fft+prep spilled -- keep kernels separate.
// R9: wfT/wiT [bq][t][4] transposes -- big win in k_beta_A.
// R10: k_inv2 streamed FFT passes (VGPR 92->64), 8 blocks/CU -- 68->~40us.
// R11 NEUTRAL: depth-1 prefetch didn't move k_gemm (latency-bound, no TLP).
// R12: yhb in MFMA-fragment order; k_gemm no-LDS no-barrier, per-lane
// perm+xor complex transform -- 55-64 -> 48.7us. Occ still 13% (2 blk/CU).
// R13: o-QUARTER split (oq 0..3, 16 outputs each): grid 512->1024 = 4
// blocks/CU -> 2x TLP for latency hiding; per-block B/MFMA halve, A re-read
// 2x (L2-cached, BW headroom confirmed by counters). Unconditional tail
// prefetch (OOB lands in adjacent allocated ws regions, values dead).
// Workspace: yhb 44.7MB | Ab 4.2MB | zh_T 11.2MB.
//   Xfb (8.4MB) + wfT (698KB) alias zh_T (lifetime fft->gemm, disjoint).
//   wiT (698KB) aliases yhb base (written after gemm, read by inv2).
// ---------------------------------------------------------------------------

typedef unsigned short u16;
typedef unsigned int   u32;
typedef __attribute__((ext_vector_type(8))) short  short8;   // 8 bf16
typedef __attribute__((ext_vector_type(4))) float  floatx4;

constexpr int LTOT = 5456;

constexpr int LB[17] = {0,1,10,35,84,165,286,455,680,969,
                        1330,1771,2300,2925,3654,4495,5456};

__device__ inline u16 f2bf(float f) {
    u32 u = __float_as_uint(f);
    u += 0x7fff + ((u >> 16) & 1);
    return (u16)(u >> 16);
}
__device__ inline u32 pack2bf(float re, float im) {
    return (u32)f2bf(re) | ((u32)f2bf(im) << 16);
}

// cc-dependent complex pack transform: cc=0 -> (re,-im) == b ^ 0x80000000;
// cc=1 -> (im,re) == ror16(b). Done as per-lane-constant perm + xor.
__device__ inline short8 btr4(uint4 q, u32 sel, u32 msk) {
    uint4 t;
    t.x = __builtin_amdgcn_perm(q.x, q.x, sel) ^ msk;
    t.y = __builtin_amdgcn_perm(q.y, q.y, sel) ^ msk;
    t.z = __builtin_amdgcn_perm(q.z, q.z, sel) ^ msk;
    t.w = __builtin_amdgcn_perm(q.w, q.w, sel) ^ msk;
    return *(short8*)&t;
}

// ---------------------------------------------------------------------------
// Wigner-table transpose: w[32][LTOT] -> wT[bq(8)][t][4] so a 4-beta group is
// one float4. Grid (22, 8) x 256.
// ---------------------------------------------------------------------------
__global__ __launch_bounds__(256) void k_wtr(const float* __restrict__ w,
                                             float* __restrict__ wT) {
    int t  = blockIdx.x * 256 + threadIdx.x;
    int bq = blockIdx.y;
    if (t < LTOT) {
        float4 v;
        v.x = w[(size_t)(bq * 4 + 0) * LTOT + t];
        v.y = w[(size_t)(bq * 4 + 1) * LTOT + t];
        v.z = w[(size_t)(bq * 4 + 2) * LTOT + t];
        v.w = w[(size_t)(bq * 4 + 3) * LTOT + t];
        *(float4*)(wT + ((size_t)bq * LTOT + t) * 4) = v;
    }
}

// ---------------------------------------------------------------------------
// Forward FFT2 (e^{-i}), radix-2 both passes, 512 threads, one task each.
// Stores ONLY Hermitian-half rows ma 0..15, bf16-packed.
// x: [z][i][b][a][g].   Xfb: [zi*32+b][ma(0..15)][ng] packed bf16 pairs.
// ---------------------------------------------------------------------------
__global__ __launch_bounds__(512) void k_fft_fwd(const float* __restrict__ x,
                                                 u32* __restrict__ Xfb) {
    __shared__ float xs[1056];               // [a][g] stride 33
    __shared__ float Gre[1056], Gim[1056];   // [a][k] stride 33
    __shared__ float Wc[32], Ws[32];
    int tid = threadIdx.x;
    if (tid < 32) {
        float sv, cv;
        sincosf(6.28318530717958647692f * (float)tid / 32.0f, &sv, &cv);
        Wc[tid] = cv; Ws[tid] = sv;
    }
    const float* src = x + (size_t)blockIdx.x * 1024;
    for (int e = tid; e < 1024; e += 512) xs[(e >> 5) * 33 + (e & 31)] = src[e];
    __syncthreads();
    // pass 1 over g (real input), radix-2: task = (a, k in 0..15)
    {
        int a = tid >> 4, k = tid & 15;
        const float* row = &xs[a * 33];
        float Er = 0.f, Ei = 0.f, Or = 0.f, Oi = 0.f;
#pragma unroll
        for (int h = 0; h < 16; h++) {
            int idx = (2 * h * k) & 31;
            float c = Wc[idx], s = Ws[idx];
            float xe = row[2 * h], xo = row[2 * h + 1];
            Er += xe * c;  Ei -= xe * s;
            Or += xo * c;  Oi -= xo * s;
        }
        float WOr = Or * Wc[k] + Oi * Ws[k];
        float WOi = Oi * Wc[k] - Or * Ws[k];
        Gre[a * 33 + k]      = Er + WOr;
        Gim[a * 33 + k]      = Ei + WOi;
        Gre[a * 33 + k + 16] = Er - WOr;
        Gim[a * 33 + k + 16] = Ei - WOi;
    }
    __syncthreads();
    // pass 2 over a, radix-2 combine; store only row ma (0..15)
    {
        u32* dst = Xfb + (size_t)blockIdx.x * 512;
        int ng = tid & 31, ma = tid >> 5;
        float Er = 0.f, Ei = 0.f, Or = 0.f, Oi = 0.f;
#pragma unroll
        for (int h = 0; h < 16; h++) {
            int idx = (2 * h * ma) & 31;
            float c = Wc[idx], s = Ws[idx];
            float er = Gre[(2 * h) * 33 + ng],      ei = Gim[(2 * h) * 33 + ng];
            float orr = Gre[(2 * h + 1) * 33 + ng], oi = Gim[(2 * h + 1) * 33 + ng];
            Er += er * c + ei * s;   Ei += ei * c - er * s;
            Or += orr * c + oi * s;  Oi += oi * c - orr * s;
        }
        float WOr = Or * Wc[ma] + Oi * Ws[ma];
        float WOi = Oi * Wc[ma] - Or * Ws[ma];
        dst[ma * 32 + ng] = pack2bf(Er + WOr, Ei + WOi);
    }
}

// ---------------------------------------------------------------------------
// Build compact bf16 yh in MFMA-FRAGMENT ORDER (R12):
// io = (i,o): i = ih*16+kh*4+j, o = oh*32+nt*8+ph
// nio = ih*1024 + oh*512 + nt*128 + kh*32 + ph*4 + j
// so k_gemm's lane fragment (4 words j=0..3) is one contiguous uint4.
// ---------------------------------------------------------------------------
__global__ __launch_bounds__(256) void k_prep_B(const float* __restrict__ Dre,
                                                const float* __restrict__ Dim,
                                                const float* __restrict__ ker,
                                                u32* __restrict__ yhb) {
    __shared__ float Ds[8][24];
    int t0  = blockIdx.x * 8;
    int tid = threadIdx.x;
    if (tid < 192) {
        int rr = tid / 24, jj = tid - rr * 24;
        Ds[rr][jj] = (jj < 12) ? Dre[(t0 + rr) * 12 + jj] : Dim[(t0 + rr) * 12 + jj - 12];
    }
    __syncthreads();
    for (int rep = 0; rep < 8; rep++) {
        int io = rep * 256 + tid;
        int i  = io >> 6, o = io & 63;
        int nio = ((i >> 4) << 10) + ((o >> 5) << 9) + (((o >> 3) & 3) << 7)
                + (((i >> 2) & 3) << 5) + ((o & 7) << 2) + (i & 3);
        const float4* kp = (const float4*)(ker + io * 12);
        float4 ka = kp[0], kb = kp[1], kc = kp[2];
        float kv[12] = {ka.x, ka.y, ka.z, ka.w, kb.x, kb.y, kb.z, kb.w,
                        kc.x, kc.y, kc.z, kc.w};
#pragma unroll
        for (int rr = 0; rr < 8; rr++) {
            float sr = 0.f, si = 0.f;
#pragma unroll
            for (int j = 0; j < 12; j++) {
                sr += Ds[rr][j]      * kv[j];
                si += Ds[rr][12 + j] * kv[j];
            }
            yhb[(size_t)(t0 + rr) * 2048 + nio] = pack2bf(sr, si);
        }
    }
}

// ---------------------------------------------------------------------------
// Fused beta-contraction + bf16 A-fragment pack. Xfb is Hermitian-half:
// rows ma 0..15 stored; ma>=17 read as conj(Xf[32-ma][(32-ng)&31]).
// Grid: (ma 32) x (zig 64) = 2048 blocks; thread = (zil 2, lq 4, ng 32).
// R9: b-loop grouped in beta-quads; wfT[bq][t][4] gives one float4 per
// (bq, l) instead of 4 scalar strided loads.
// ---------------------------------------------------------------------------
__global__ __launch_bounds__(256) void k_beta_A(const u32* __restrict__ Xfb,
                                                const float* __restrict__ wfT,
                                                u16* __restrict__ Ab) {
    int ma  = blockIdx.x >> 6;
    int zig = blockIdx.x & 63;
    int tid = threadIdx.x;
    int ng  = tid & 31;
    int lq  = (tid >> 5) & 3;
    int zil = tid >> 7;
    int zi  = zig * 2 + zil;
    int z = zi >> 5, i = zi & 31;
    int mh = (ma <= 15) ? ma : ma - 32;
    int nh = (ng <= 15) ? ng : ng - 32;
    int am = mh < 0 ? -mh : mh;
    int an = nh < 0 ? -nh : nh;
    int l0 = am > an ? am : an;
    int lb = lq * 4;

    int isconj = (ma > 16);
    int mau = isconj ? (32 - ma) : ma;
    int ngu = isconj ? ((32 - ng) & 31) : ng;
    if (mau > 15) { mau = 0; ngu = 0; }   // ma==16: l0==16, values unused

    int tl[4];
#pragma unroll
    for (int j = 0; j < 4; j++) {
        int l = lb + j;
        tl[j] = LB[l] + (mh + l) * (2 * l + 1) + (nh + l);
    }
    float2 acc[4];
#pragma unroll
    for (int j = 0; j < 4; j++) acc[j] = make_float2(0.f, 0.f);

    const u32* xp = Xfb + (size_t)zi * 32 * 512 + mau * 32 + ngu;
    float sgn = isconj ? -1.f : 1.f;
#pragma unroll 2
    for (int bq = 0; bq < 8; bq++) {
        u32 p0 = xp[(size_t)(4 * bq + 0) * 512];
        u32 p1 = xp[(size_t)(4 * bq + 1) * 512];
        u32 p2 = xp[(size_t)(4 * bq + 2) * 512];
        u32 p3 = xp[(size_t)(4 * bq + 3) * 512];
        float vx0 = __uint_as_float(p0 << 16);
        float vy0 = sgn * __uint_as_float(p0 & 0xffff0000u);
        float vx1 = __uint_as_float(p1 << 16);
        float vy1 = sgn * __uint_as_float(p1 & 0xffff0000u);
        float vx2 = __uint_as_float(p2 << 16);
        float vy2 = sgn * __uint_as_float(p2 & 0xffff0000u);
        float vx3 = __uint_as_float(p3 << 16);
        float vy3 = sgn * __uint_as_float(p3 & 0xffff0000u);
        const float4* wq = (const float4*)(wfT + (size_t)bq * (LTOT * 4));
#pragma unroll
        for (int j = 0; j < 4; j++) {
            if (lb + j >= l0) {
                float4 w = wq[tl[j]];
                acc[j].x += w.x * vx0 + w.y * vx1 + w.z * vx2 + w.w * vx3;
                acc[j].y += w.x * vy0 + w.y * vy1 + w.z * vy2 + w.w * vy3;
            }
        }
    }
    int s_i  = i >> 4;
    int kl   = 2 * (i & 15);
    int joff = kl & 7;
    int Lhi  = (kl >> 3) << 4;
#pragma unroll
    for (int j = 0; j < 4; j++) {
        int l = lb + j;
        if (l >= l0) {
            int mi = mh + l, ni = nh + l;
            int s   = 2 * ni + s_i;
            int row = 4 * mi + z;
            u32 pack = pack2bf(acc[j].x, acc[j].y);
            size_t off = (size_t)8192 * l * l + (size_t)s * 4096
                       + ((row >> 4) << 9) + ((Lhi + (row & 15)) << 3) + joff;
            *(u32*)(Ab + off) = pack;
        }
    }
}

// ---------------------------------------------------------------------------
// MFMA GEMM, R13: o-quarter split. 1024 blocks = sum_l 4*(2l+1), big l first:
// block = (l, n, oq). NO LDS, NO barriers; B-fragments contiguous uint4 from
// fragment-ordered yhb; per-lane perm+xor complex transform; 2-deep named-
// register pipeline with unconditional tail prefetch (OOB reads land in
// adjacent allocated ws regions; values dead).
// Output transposed: zh_T[zo][t] (float pairs).
// ---------------------------------------------------------------------------
__global__ __launch_bounds__(256) void k_gemm(const u16* __restrict__ Ab,
                                              const u32* __restrict__ yhb,
                                              float* __restrict__ zhT) {
    int rem = blockIdx.x, l, nl = 1;
    for (l = 15; l >= 0; l--) {
        nl = 2 * l + 1;
        int c = nl * 4;
        if (rem < c) break;
        rem -= c;
    }
    int n  = rem >> 2;
    int oq = rem & 3;
    int base = LB[l];
    const u16* Ag = Ab + (size_t)8192 * l * l;
    int S = 2 * nl;

    int tid = threadIdx.x, lane = tid & 63, w = tid >> 6;
    int cc = lane & 1;
    u32 sel = cc ? 0x01000302u : 0x03020100u;   // ror16 : identity
    u32 msk = cc ? 0u          : 0x80000000u;   // 0     : negate-hi

    // B: per step s=(k,ih): uint4 at yhb32 + (base+k*nl+n)*2048 + ih*1024
    //    + oq*256 + (lane>>1)*4, nt-stride 128 u32 (32 uint4).
    const u32* Bb = yhb + (size_t)(base + n) * 2048 + (oq << 8) + ((lane >> 1) << 2);
    const u16* Aw = Ag + ((w << 10) | (lane << 3));

    floatx4 acc[2][2];
#pragma unroll
    for (int a = 0; a < 2; a++)
#pragma unroll
        for (int b = 0; b < 2; b++) acc[a][b] = (floatx4)0.f;

#define LOADB(s, q0, q1) { \
    const uint4* bp = (const uint4*)(Bb + (size_t)((s) >> 1) * nl * 2048 + (((s) & 1) << 10)); \
    q0 = bp[0]; q1 = bp[32]; }
#define LOADA(s, r0, r1) { \
    const u16* apx = Aw + (size_t)(s) * 4096; \
    r0 = *(const short8*)apx; r1 = *(const short8*)(apx + 512); }
#define MF(a, b, c) __builtin_amdgcn_mfma_f32_16x16x32_bf16(a, b, c, 0, 0, 0)

    uint4 eB0, eB1; short8 ea0, ea1;   // even-step raw
    uint4 oB0, oB1; short8 oa0, oa1;   // odd-step raw
    LOADA(0, ea0, ea1); LOADB(0, eB0, eB1);
    LOADA(1, oa0, oa1); LOADB(1, oB0, oB1);

    for (int s = 0; s < S; s += 2) {
        // even step: transform (waits on its loads), refill regs, then MFMA
        short8 bf0 = btr4(eB0, sel, msk), bf1 = btr4(eB1, sel, msk);
        short8 af0 = ea0, af1 = ea1;
        LOADA(s + 2, ea0, ea1); LOADB(s + 2, eB0, eB1);
        acc[0][0] = MF(af0, bf0, acc[0][0]);  acc[1][0] = MF(af1, bf0, acc[1][0]);
        acc[0][1] = MF(af0, bf1, acc[0][1]);  acc[1][1] = MF(af1, bf1, acc[1][1]);
        // odd step
        short8 cf0 = btr4(oB0, sel, msk), cf1 = btr4(oB1, sel, msk);
        short8 ag0 = oa0, ag1 = oa1;
        LOADA(s + 3, oa0, oa1); LOADB(s + 3, oB0, oB1);
        acc[0][0] = MF(ag0, cf0, acc[0][0]);  acc[1][0] = MF(ag1, cf0, acc[1][0]);
        acc[0][1] = MF(ag0, cf1, acc[0][1]);  acc[1][1] = MF(ag1, cf1, acc[1][1]);
    }
#undef LOADB
#undef LOADA
#undef MF

    int q = lane >> 4, cn = lane & 15;
#pragma unroll
    for (int mt = 0; mt < 2; mt++) {
#pragma unroll
        for (int nt = 0; nt < 2; nt++) {
            int nu2 = (nt << 4) + cn;
            int o2  = (oq << 4) + (nu2 >> 1);
            int c2  = nu2 & 1;
#pragma unroll
            for (int r = 0; r < 4; r++) {
                int R = (w << 5) + (mt << 4) + (q << 2) + r;
                int m = R >> 2, z = R & 3;
                if (m < nl) {
                    int t  = base + m * nl + n;
                    int zo = (z << 6) + o2;
                    zhT[((size_t)zo * LTOT + t) * 2 + c2] = acc[mt][nt][r];
                }
            }
        }
    }
}

// ---------------------------------------------------------------------------
// Inverse, 4 betas per block: shared zv loads across betas, direct pass-2
// global write. R9: wiT[bq][t][4] -> one float4 per (l,t).
// R10: streamed FFT passes (no row[32]/col[16] staging) -> VGPR <=64,
// __launch_bounds__(256,8) -> 8 blocks/CU. bq-major block map: the 8 blocks
// sharing one zhT row have ids zo+256*bq == zo (mod 8) -> same XCD L2.
// Grid: 2048 = (bq 8) x (zo 256); 256 threads; LDS ~17 KB.
// ---------------------------------------------------------------------------
__global__ __launch_bounds__(256, 8) void k_inv2(const float2* __restrict__ zhT,
                                                 const float* __restrict__ wiT,
                                                 const float* __restrict__ bias,
                                                 float* __restrict__ out) {
    __shared__ float2 Pb[4 * 528];   // plane p at p*528, rows ma 0..15 stride 33
    __shared__ float Wc[32], Ws[32];
    int tid = threadIdx.x;
    int zo = blockIdx.x & 255;
    int bq = blockIdx.x >> 8;
    int b0 = bq * 4;
    if (tid < 32) {
        float sv, cv;
        sincosf(6.28318530717958647692f * (float)tid / 32.0f, &sv, &cv);
        Wc[tid] = cv; Ws[tid] = sv;
    }
    // ---- gather: thread = (ng 32, rq 8); 2 ma-rows; 4 betas share each zv
    {
        int ng = tid & 31, rq = tid >> 5;
        int nh = (ng <= 15) ? ng : ng - 32;
        int an = nh < 0 ? -nh : nh;
        const float2* zr = zhT + (size_t)zo * LTOT;
        const float4* wp = (const float4*)(wiT + (size_t)bq * (LTOT * 4));
#pragma unroll
        for (int mr = 0; mr < 2; mr++) {
            int ma = rq + 8 * mr;
            int l0 = ma > an ? ma : an;
            float2 a0 = make_float2(0.f, 0.f), a1 = a0, a2 = a0, a3 = a0;
#pragma unroll 4
            for (int l = 0; l < 16; l++) {
                if (l >= l0) {
                    int t = LB[l] + (ma + l) * (2 * l + 1) + (nh + l);
                    float2 zv = zr[t];
                    float4 w = wp[t];
                    a0.x += w.x * zv.x; a0.y += w.x * zv.y;
                    a1.x += w.y * zv.x; a1.y += w.y * zv.y;
                    a2.x += w.z * zv.x; a2.y += w.z * zv.y;
                    a3.x += w.w * zv.x; a3.y += w.w * zv.y;
                }
            }
            int po = ma * 33 + ng;
            Pb[po]            = a0;
            Pb[528 + po]      = a1;
            Pb[2 * 528 + po]  = a2;
            Pb[3 * 528 + po]  = a3;
        }
    }
    __syncthreads();
    // ---- pass 1 (ng -> g), radix-2, in-place: 64 rows x 8 thr = 512 tasks.
    // Streamed: read each LDS value once, accumulate E/O for k and k+8.
    // Row-sharing threads are one wave (lockstep); reads precede writes in
    // program order, so in-place update stays race-free.
#pragma unroll
    for (int it = 0; it < 2; it++) {
        int task = tid + it * 256;
        int rowid = task >> 3, q = task & 7;
        float2* prow = &Pb[(rowid >> 4) * 528 + (rowid & 15) * 33];
        float2 E0 = make_float2(0.f, 0.f), O0 = E0, E1 = E0, O1 = E0;
        int k1 = q + 8;
#pragma unroll 4
        for (int h = 0; h < 16; h++) {
            float2 e = prow[2 * h], o = prow[2 * h + 1];
            int i0 = (2 * h * q) & 31;
            int i1 = (2 * h * k1) & 31;
            float c0 = Wc[i0], s0 = Ws[i0];
            float c1 = Wc[i1], s1 = Ws[i1];
            E0.x += e.x * c0 - e.y * s0;  E0.y += e.x * s0 + e.y * c0;
            O0.x += o.x * c0 - o.y * s0;  O0.y += o.x * s0 + o.y * c0;
            E1.x += e.x * c1 - e.y * s1;  E1.y += e.x * s1 + e.y * c1;
            O1.x += o.x * c1 - o.y * s1;  O1.y += o.x * s1 + o.y * c1;
        }
        float c0 = Wc[q],  s0 = Ws[q];
        float c1 = Wc[k1], s1 = Ws[k1];
        float2 w0 = make_float2(O0.x * c0 - O0.y * s0, O0.x * s0 + O0.y * c0);
        float2 w1 = make_float2(O1.x * c1 - O1.y * s1, O1.x * s1 + O1.y * c1);
        prow[q]      = make_float2(E0.x + w0.x, E0.y + w0.y);
        prow[q + 16] = make_float2(E0.x - w0.x, E0.y - w0.y);
        prow[q + 8]  = make_float2(E1.x + w1.x, E1.y + w1.y);
        prow[q + 24] = make_float2(E1.x - w1.x, E1.y - w1.y);
    }
    __syncthreads();
    // ---- pass 2 (ma -> a): streamed even/odd column reads, direct store
    float bv = bias[zo & 63];
#pragma unroll
    for (int it = 0; it < 2; it++) {
        int task = tid + it * 256;
        int p = task >> 7, rr = task & 127;
        int qa = rr >> 5, g = rr & 31;
        const float2* pc = &Pb[p * 528];
        float2 c0 = pc[g];
        float Ea[4], Oa[4];
#pragma unroll
        for (int jj = 0; jj < 4; jj++) { Ea[jj] = c0.x; Oa[jj] = 0.f; }
#pragma unroll 4
        for (int j = 1; j < 8; j++) {
            float2 c = pc[(2 * j) * 33 + g];
#pragma unroll
            for (int jj = 0; jj < 4; jj++) {
                int a = qa * 4 + jj;
                int idx = ((2 * j) * a) & 31;
                Ea[jj] += 2.f * (c.x * Wc[idx] - c.y * Ws[idx]);
            }
        }
#pragma unroll 4
        for (int j = 0; j < 8; j++) {
            float2 c = pc[(2 * j + 1) * 33 + g];
#pragma unroll
            for (int jj = 0; jj < 4; jj++) {
                int a = qa * 4 + jj;
                int idx = ((2 * j + 1) * a) & 31;
                Oa[jj] += 2.f * (c.x * Wc[idx] - c.y * Ws[idx]);
            }
        }
        float* dst = out + (size_t)zo * 32768 + (size_t)(b0 + p) * 1024;
#pragma unroll
        for (int jj = 0; jj < 4; jj++) {
            int a = qa * 4 + jj;
            dst[a * 32 + g]        = (Ea[jj] + Oa[jj]) * (1.f / 1024.f) + bv;
            dst[(a + 16) * 32 + g] = (Ea[jj] - Oa[jj]) * (1.f / 1024.f) + bv;
        }
    }
}

// ---------------------------------------------------------------------------
extern "C" void kernel_launch(void* const* d_in, const int* in_sizes, int n_in,
                              void* d_out, int out_size, void* d_ws, size_t ws_size,
                              hipStream_t stream) {
    const float* x    = (const float*)d_in[0];
    const float* ker  = (const float*)d_in[1];
    const float* bias = (const float*)d_in[2];
    const float* wf   = (const float*)d_in[3];
    const float* wi   = (const float*)d_in[4];
    const float* Dre  = (const float*)d_in[5];
    const float* Dim  = (const float*)d_in[6];
    float* out = (float*)d_out;

    // layout: yhb 44.7MB | Ab 4.2MB | zh_T 11.2MB.
    // Xfb (8.4MB) + wfT (698KB, at zhT+8.39MB) alias zh_T: both dead once
    // k_gemm writes zhT. wiT (698KB) aliases yhb base: written after k_gemm
    // (yhb dead), read by k_inv2.
    char* ws = (char*)d_ws;
    u32*    yhb = (u32*)ws;
    u16*    Ab  = (u16*)(ws + 44695552);
    float*  zhT = (float*)(ws + 44695552 + 4194304);
    u32*    Xfb = (u32*)zhT;                                    // disjoint lifetime vs zh_T
    float*  wfT = (float*)(ws + 44695552 + 4194304 + 8388608);  // zhT tail, pre-gemm
    float*  wiT = (float*)ws;                                   // yhb region, post-gemm

    hipLaunchKernelGGL(k_fft_fwd, dim3(4096),  dim3(512), 0, stream, x, Xfb);
    hipLaunchKernelGGL(k_wtr,     dim3(22, 8), dim3(256), 0, stream, wf, wfT);
    hipLaunchKernelGGL(k_prep_B,  dim3(682),   dim3(256), 0, stream, Dre, Dim, ker, yhb);
    hipLaunchKernelGGL(k_beta_A,  dim3(2048),  dim3(256), 0, stream, Xfb, wfT, Ab);
    hipLaunchKernelGGL(k_gemm,    dim3(1024),  dim3(256), 0, stream, Ab, yhb, zhT);
    hipLaunchKernelGGL(k_wtr,     dim3(22, 8), dim3(256), 0, stream, wi, wiT);
    hipLaunchKernelGGL(k_inv2,    dim3(2048),  dim3(256), 0, stream,
                       (const float2*)zhT, wiT, bias, out);
}

// Round 6
// 201.310 us; speedup vs baseline: 1.1930x; 1.0995x over previous
//
#include <hip/hip_runtime.h>
#include <math.h>

// ---------------------------------------------------------------------------
// SO3 convolution. bf16 MFMA GEMM (complex-as-real); Hermitian-half FFT/IFFT.
// Pipeline: k_fft_fwd (Hermitian bf16 out) -> k_wtr(wf) -> k_prep_B
//           -> k_beta_A -> k_gemm (MFMA) -> k_wtr(wi) -> k_inv2
// R8 lesson: fusing fft+prep spilled -- keep kernels separate.
// R9: wfT/wiT [bq][t][4] transposes -- big win in k_beta_A.
// R10: k_inv2 streamed FFT passes (VGPR 92->64), 8 blocks/CU -- 68->~40us.
// R11 NEUTRAL: depth-1 prefetch didn't move k_gemm (latency-bound, no TLP).
// R12: yhb in MFMA-fragment order; k_gemm no-LDS no-barrier -- ~49us.
// R13: k_gemm o-quarter split, 1024 blocks = 4/CU.
// R14: k_inv2 was LDS-pipe + VALU-overhead bound (~80% of issue was twiddle
// ds_reads + index math, not FMA). v_pk_fma_f32 complex MACs (op_sel
// broadcasts, neg_lo signs -- 2 instr/cmac, no movs); twiddles as register
// rotation chains (t*=r) + (-1)^h / i-rotation symmetries -> pass1 zero
// twiddle LDS, pass2 135->15 LDS ops/task; stride-34 rows -> b128 loads.
// Workspace: yhb 44.7MB | Ab 4.2MB | zh_T 11.2MB.
//   Xfb (8.4MB) + wfT (698KB) alias zh_T (lifetime fft->gemm, disjoint).
//   wiT (698KB) aliases yhb base (written after gemm, read by inv2).
// ---------------------------------------------------------------------------

typedef unsigned short u16;
typedef unsigned int   u32;
typedef __attribute__((ext_vector_type(8))) short  short8;   // 8 bf16
typedef __attribute__((ext_vector_type(4))) float  floatx4;
typedef __attribute__((ext_vector_type(2))) float  f32x2;

constexpr int LTOT = 5456;

constexpr int LB[17] = {0,1,10,35,84,165,286,455,680,969,
                        1330,1771,2300,2925,3654,4495,5456};

__device__ inline u16 f2bf(float f) {
    u32 u = __float_as_uint(f);
    u += 0x7fff + ((u >> 16) & 1);
    return (u16)(u >> 16);
}
__device__ inline u32 pack2bf(float re, float im) {
    return (u32)f2bf(re) | ((u32)f2bf(im) << 16);
}

// cc-dependent complex pack transform: cc=0 -> (re,-im) == b ^ 0x80000000;
// cc=1 -> (im,re) == ror16(b). Done as per-lane-constant perm + xor.
__device__ inline short8 btr4(uint4 q, u32 sel, u32 msk) {
    uint4 t;
    t.x = __builtin_amdgcn_perm(q.x, q.x, sel) ^ msk;
    t.y = __builtin_amdgcn_perm(q.y, q.y, sel) ^ msk;
    t.z = __builtin_amdgcn_perm(q.z, q.z, sel) ^ msk;
    t.w = __builtin_amdgcn_perm(q.w, q.w, sel) ^ msk;
    return *(short8*)&t;
}

// ---- packed-fp32 complex helpers (VOP3P). acc/result = (re, im) pairs. ----
// acc += e * t (complex):  lo: +e.x*t.x - e.y*t.y ; hi: +e.x*t.y + e.y*t.x
__device__ __forceinline__ f32x2 cfma(f32x2 e, f32x2 t, f32x2 acc) {
    asm("v_pk_fma_f32 %0, %1, %2, %0 op_sel:[0,0,0] op_sel_hi:[0,1,1]\n\t"
        "v_pk_fma_f32 %0, %1, %2, %0 op_sel:[1,1,0] op_sel_hi:[1,0,1] neg_lo:[0,1,0]"
        : "+v"(acc) : "v"(e), "v"(t));
    return acc;
}
// d = t * r (complex multiply)
__device__ __forceinline__ f32x2 cmulp(f32x2 t, f32x2 r) {
    f32x2 d;
    asm("v_pk_mul_f32 %0, %1, %2 op_sel:[0,0] op_sel_hi:[0,1]\n\t"
        "v_pk_fma_f32 %0, %1, %2, %0 op_sel:[1,1,0] op_sel_hi:[1,0,1] neg_lo:[0,1,0]"
        : "=&v"(d) : "v"(t), "v"(r));
    return d;
}
// acc += w2.lo * v   /   acc += w2.hi * v   (scalar-broadcast * vector)
__device__ __forceinline__ f32x2 fma_bl(f32x2 w2, f32x2 v, f32x2 acc) {
    asm("v_pk_fma_f32 %0, %1, %2, %0 op_sel:[0,0,0] op_sel_hi:[0,1,1]"
        : "+v"(acc) : "v"(w2), "v"(v));
    return acc;
}
__device__ __forceinline__ f32x2 fma_bh(f32x2 w2, f32x2 v, f32x2 acc) {
    asm("v_pk_fma_f32 %0, %1, %2, %0 op_sel:[1,0,0] op_sel_hi:[1,1,1]"
        : "+v"(acc) : "v"(w2), "v"(v));
    return acc;
}

// ---------------------------------------------------------------------------
// Wigner-table transpose: w[32][LTOT] -> wT[bq(8)][t][4] so a 4-beta group is
// one float4. Grid (22, 8) x 256.
// ---------------------------------------------------------------------------
__global__ __launch_bounds__(256) void k_wtr(const float* __restrict__ w,
                                             float* __restrict__ wT) {
    int t  = blockIdx.x * 256 + threadIdx.x;
    int bq = blockIdx.y;
    if (t < LTOT) {
        float4 v;
        v.x = w[(size_t)(bq * 4 + 0) * LTOT + t];
        v.y = w[(size_t)(bq * 4 + 1) * LTOT + t];
        v.z = w[(size_t)(bq * 4 + 2) * LTOT + t];
        v.w = w[(size_t)(bq * 4 + 3) * LTOT + t];
        *(float4*)(wT + ((size_t)bq * LTOT + t) * 4) = v;
    }
}

// ---------------------------------------------------------------------------
// Forward FFT2 (e^{-i}), radix-2 both passes, 512 threads, one task each.
// Stores ONLY Hermitian-half rows ma 0..15, bf16-packed.
// x: [z][i][b][a][g].   Xfb: [zi*32+b][ma(0..15)][ng] packed bf16 pairs.
// ---------------------------------------------------------------------------
__global__ __launch_bounds__(512) void k_fft_fwd(const float* __restrict__ x,
                                                 u32* __restrict__ Xfb) {
    __shared__ float xs[1056];               // [a][g] stride 33
    __shared__ float Gre[1056], Gim[1056];   // [a][k] stride 33
    __shared__ float Wc[32], Ws[32];
    int tid = threadIdx.x;
    if (tid < 32) {
        float sv, cv;
        sincosf(6.28318530717958647692f * (float)tid / 32.0f, &sv, &cv);
        Wc[tid] = cv; Ws[tid] = sv;
    }
    const float* src = x + (size_t)blockIdx.x * 1024;
    for (int e = tid; e < 1024; e += 512) xs[(e >> 5) * 33 + (e & 31)] = src[e];
    __syncthreads();
    // pass 1 over g (real input), radix-2: task = (a, k in 0..15)
    {
        int a = tid >> 4, k = tid & 15;
        const float* row = &xs[a * 33];
        float Er = 0.f, Ei = 0.f, Or = 0.f, Oi = 0.f;
#pragma unroll
        for (int h = 0; h < 16; h++) {
            int idx = (2 * h * k) & 31;
            float c = Wc[idx], s = Ws[idx];
            float xe = row[2 * h], xo = row[2 * h + 1];
            Er += xe * c;  Ei -= xe * s;
            Or += xo * c;  Oi -= xo * s;
        }
        float WOr = Or * Wc[k] + Oi * Ws[k];
        float WOi = Oi * Wc[k] - Or * Ws[k];
        Gre[a * 33 + k]      = Er + WOr;
        Gim[a * 33 + k]      = Ei + WOi;
        Gre[a * 33 + k + 16] = Er - WOr;
        Gim[a * 33 + k + 16] = Ei - WOi;
    }
    __syncthreads();
    // pass 2 over a, radix-2 combine; store only row ma (0..15)
    {
        u32* dst = Xfb + (size_t)blockIdx.x * 512;
        int ng = tid & 31, ma = tid >> 5;
        float Er = 0.f, Ei = 0.f, Or = 0.f, Oi = 0.f;
#pragma unroll
        for (int h = 0; h < 16; h++) {
            int idx = (2 * h * ma) & 31;
            float c = Wc[idx], s = Ws[idx];
            float er = Gre[(2 * h) * 33 + ng],      ei = Gim[(2 * h) * 33 + ng];
            float orr = Gre[(2 * h + 1) * 33 + ng], oi = Gim[(2 * h + 1) * 33 + ng];
            Er += er * c + ei * s;   Ei += ei * c - er * s;
            Or += orr * c + oi * s;  Oi += oi * c - orr * s;
        }
        float WOr = Or * Wc[ma] + Oi * Ws[ma];
        float WOi = Oi * Wc[ma] - Or * Ws[ma];
        dst[ma * 32 + ng] = pack2bf(Er + WOr, Ei + WOi);
    }
}

// ---------------------------------------------------------------------------
// Build compact bf16 yh in MFMA-FRAGMENT ORDER (R12):
// io = (i,o): i = ih*16+kh*4+j, o = oh*32+nt*8+ph
// nio = ih*1024 + oh*512 + nt*128 + kh*32 + ph*4 + j
// so k_gemm's lane fragment (4 words j=0..3) is one contiguous uint4.
// ---------------------------------------------------------------------------
__global__ __launch_bounds__(256) void k_prep_B(const float* __restrict__ Dre,
                                                const float* __restrict__ Dim,
                                                const float* __restrict__ ker,
                                                u32* __restrict__ yhb) {
    __shared__ float Ds[8][24];
    int t0  = blockIdx.x * 8;
    int tid = threadIdx.x;
    if (tid < 192) {
        int rr = tid / 24, jj = tid - rr * 24;
        Ds[rr][jj] = (jj < 12) ? Dre[(t0 + rr) * 12 + jj] : Dim[(t0 + rr) * 12 + jj - 12];
    }
    __syncthreads();
    for (int rep = 0; rep < 8; rep++) {
        int io = rep * 256 + tid;
        int i  = io >> 6, o = io & 63;
        int nio = ((i >> 4) << 10) + ((o >> 5) << 9) + (((o >> 3) & 3) << 7)
                + (((i >> 2) & 3) << 5) + ((o & 7) << 2) + (i & 3);
        const float4* kp = (const float4*)(ker + io * 12);
        float4 ka = kp[0], kb = kp[1], kc = kp[2];
        float kv[12] = {ka.x, ka.y, ka.z, ka.w, kb.x, kb.y, kb.z, kb.w,
                        kc.x, kc.y, kc.z, kc.w};
#pragma unroll
        for (int rr = 0; rr < 8; rr++) {
            float sr = 0.f, si = 0.f;
#pragma unroll
            for (int j = 0; j < 12; j++) {
                sr += Ds[rr][j]      * kv[j];
                si += Ds[rr][12 + j] * kv[j];
            }
            yhb[(size_t)(t0 + rr) * 2048 + nio] = pack2bf(sr, si);
        }
    }
}

// ---------------------------------------------------------------------------
// Fused beta-contraction + bf16 A-fragment pack. Xfb is Hermitian-half:
// rows ma 0..15 stored; ma>=17 read as conj(Xf[32-ma][(32-ng)&31]).
// Grid: (ma 32) x (zig 64) = 2048 blocks; thread = (zil 2, lq 4, ng 32).
// R9: b-loop grouped in beta-quads; wfT[bq][t][4] gives one float4 per
// (bq, l) instead of 4 scalar strided loads.
// ---------------------------------------------------------------------------
__global__ __launch_bounds__(256) void k_beta_A(const u32* __restrict__ Xfb,
                                                const float* __restrict__ wfT,
                                                u16* __restrict__ Ab) {
    int ma  = blockIdx.x >> 6;
    int zig = blockIdx.x & 63;
    int tid = threadIdx.x;
    int ng  = tid & 31;
    int lq  = (tid >> 5) & 3;
    int zil = tid >> 7;
    int zi  = zig * 2 + zil;
    int z = zi >> 5, i = zi & 31;
    int mh = (ma <= 15) ? ma : ma - 32;
    int nh = (ng <= 15) ? ng : ng - 32;
    int am = mh < 0 ? -mh : mh;
    int an = nh < 0 ? -nh : nh;
    int l0 = am > an ? am : an;
    int lb = lq * 4;

    int isconj = (ma > 16);
    int mau = isconj ? (32 - ma) : ma;
    int ngu = isconj ? ((32 - ng) & 31) : ng;
    if (mau > 15) { mau = 0; ngu = 0; }   // ma==16: l0==16, values unused

    int tl[4];
#pragma unroll
    for (int j = 0; j < 4; j++) {
        int l = lb + j;
        tl[j] = LB[l] + (mh + l) * (2 * l + 1) + (nh + l);
    }
    float2 acc[4];
#pragma unroll
    for (int j = 0; j < 4; j++) acc[j] = make_float2(0.f, 0.f);

    const u32* xp = Xfb + (size_t)zi * 32 * 512 + mau * 32 + ngu;
    float sgn = isconj ? -1.f : 1.f;
#pragma unroll 2
    for (int bq = 0; bq < 8; bq++) {
        u32 p0 = xp[(size_t)(4 * bq + 0) * 512];
        u32 p1 = xp[(size_t)(4 * bq + 1) * 512];
        u32 p2 = xp[(size_t)(4 * bq + 2) * 512];
        u32 p3 = xp[(size_t)(4 * bq + 3) * 512];
        float vx0 = __uint_as_float(p0 << 16);
        float vy0 = sgn * __uint_as_float(p0 & 0xffff0000u);
        float vx1 = __uint_as_float(p1 << 16);
        float vy1 = sgn * __uint_as_float(p1 & 0xffff0000u);
        float vx2 = __uint_as_float(p2 << 16);
        float vy2 = sgn * __uint_as_float(p2 & 0xffff0000u);
        float vx3 = __uint_as_float(p3 << 16);
        float vy3 = sgn * __uint_as_float(p3 & 0xffff0000u);
        const float4* wq = (const float4*)(wfT + (size_t)bq * (LTOT * 4));
#pragma unroll
        for (int j = 0; j < 4; j++) {
            if (lb + j >= l0) {
                float4 w = wq[tl[j]];
                acc[j].x += w.x * vx0 + w.y * vx1 + w.z * vx2 + w.w * vx3;
                acc[j].y += w.x * vy0 + w.y * vy1 + w.z * vy2 + w.w * vy3;
            }
        }
    }
    int s_i  = i >> 4;
    int kl   = 2 * (i & 15);
    int joff = kl & 7;
    int Lhi  = (kl >> 3) << 4;
#pragma unroll
    for (int j = 0; j < 4; j++) {
        int l = lb + j;
        if (l >= l0) {
            int mi = mh + l, ni = nh + l;
            int s   = 2 * ni + s_i;
            int row = 4 * mi + z;
            u32 pack = pack2bf(acc[j].x, acc[j].y);
            size_t off = (size_t)8192 * l * l + (size_t)s * 4096
                       + ((row >> 4) << 9) + ((Lhi + (row & 15)) << 3) + joff;
            *(u32*)(Ab + off) = pack;
        }
    }
}

// ---------------------------------------------------------------------------
// MFMA GEMM, R13: o-quarter split. 1024 blocks = sum_l 4*(2l+1), big l first:
// block = (l, n, oq). NO LDS, NO barriers; B-fragments contiguous uint4 from
// fragment-ordered yhb; per-lane perm+xor complex transform; 2-deep named-
// register pipeline with unconditional tail prefetch (OOB reads land in
// adjacent allocated ws regions; values dead).
// Output transposed: zh_T[zo][t] (float pairs).
// ---------------------------------------------------------------------------
__global__ __launch_bounds__(256) void k_gemm(const u16* __restrict__ Ab,
                                              const u32* __restrict__ yhb,
                                              float* __restrict__ zhT) {
    int rem = blockIdx.x, l, nl = 1;
    for (l = 15; l >= 0; l--) {
        nl = 2 * l + 1;
        int c = nl * 4;
        if (rem < c) break;
        rem -= c;
    }
    int n  = rem >> 2;
    int oq = rem & 3;
    int base = LB[l];
    const u16* Ag = Ab + (size_t)8192 * l * l;
    int S = 2 * nl;

    int tid = threadIdx.x, lane = tid & 63, w = tid >> 6;
    int cc = lane & 1;
    u32 sel = cc ? 0x01000302u : 0x03020100u;   // ror16 : identity
    u32 msk = cc ? 0u          : 0x80000000u;   // 0     : negate-hi

    // B: per step s=(k,ih): uint4 at yhb32 + (base+k*nl+n)*2048 + ih*1024
    //    + oq*256 + (lane>>1)*4, nt-stride 128 u32 (32 uint4).
    const u32* Bb = yhb + (size_t)(base + n) * 2048 + (oq << 8) + ((lane >> 1) << 2);
    const u16* Aw = Ag + ((w << 10) | (lane << 3));

    floatx4 acc[2][2];
#pragma unroll
    for (int a = 0; a < 2; a++)
#pragma unroll
        for (int b = 0; b < 2; b++) acc[a][b] = (floatx4)0.f;

#define LOADB(s, q0, q1) { \
    const uint4* bp = (const uint4*)(Bb + (size_t)((s) >> 1) * nl * 2048 + (((s) & 1) << 10)); \
    q0 = bp[0]; q1 = bp[32]; }
#define LOADA(s, r0, r1) { \
    const u16* apx = Aw + (size_t)(s) * 4096; \
    r0 = *(const short8*)apx; r1 = *(const short8*)(apx + 512); }
#define MF(a, b, c) __builtin_amdgcn_mfma_f32_16x16x32_bf16(a, b, c, 0, 0, 0)

    uint4 eB0, eB1; short8 ea0, ea1;   // even-step raw
    uint4 oB0, oB1; short8 oa0, oa1;   // odd-step raw
    LOADA(0, ea0, ea1); LOADB(0, eB0, eB1);
    LOADA(1, oa0, oa1); LOADB(1, oB0, oB1);

    for (int s = 0; s < S; s += 2) {
        // even step: transform (waits on its loads), refill regs, then MFMA
        short8 bf0 = btr4(eB0, sel, msk), bf1 = btr4(eB1, sel, msk);
        short8 af0 = ea0, af1 = ea1;
        LOADA(s + 2, ea0, ea1); LOADB(s + 2, eB0, eB1);
        acc[0][0] = MF(af0, bf0, acc[0][0]);  acc[1][0] = MF(af1, bf0, acc[1][0]);
        acc[0][1] = MF(af0, bf1, acc[0][1]);  acc[1][1] = MF(af1, bf1, acc[1][1]);
        // odd step
        short8 cf0 = btr4(oB0, sel, msk), cf1 = btr4(oB1, sel, msk);
        short8 ag0 = oa0, ag1 = oa1;
        LOADA(s + 3, oa0, oa1); LOADB(s + 3, oB0, oB1);
        acc[0][0] = MF(ag0, cf0, acc[0][0]);  acc[1][0] = MF(ag1, cf0, acc[1][0]);
        acc[0][1] = MF(ag0, cf1, acc[0][1]);  acc[1][1] = MF(ag1, cf1, acc[1][1]);
    }
#undef LOADB
#undef LOADA
#undef MF

    int q = lane >> 4, cn = lane & 15;
#pragma unroll
    for (int mt = 0; mt < 2; mt++) {
#pragma unroll
        for (int nt = 0; nt < 2; nt++) {
            int nu2 = (nt << 4) + cn;
            int o2  = (oq << 4) + (nu2 >> 1);
            int c2  = nu2 & 1;
#pragma unroll
            for (int r = 0; r < 4; r++) {
                int R = (w << 5) + (mt << 4) + (q << 2) + r;
                int m = R >> 2, z = R & 3;
                if (m < nl) {
                    int t  = base + m * nl + n;
                    int zo = (z << 6) + o2;
                    zhT[((size_t)zo * LTOT + t) * 2 + c2] = acc[mt][nt][r];
                }
            }
        }
    }
}

// ---------------------------------------------------------------------------
// Inverse, 4 betas per block. R14: packed-fp32 complex math throughout.
// gather: v_pk_fma broadcast MACs (4 instr per (l,t) instead of 8 FMA).
// pass 1 (g-DFT): per task accumulate Ep/En/Op/On (h even/odd split exploits
// W^{2h(q+8)} = (-1)^h W^{2hq}); twiddle = register rotation chain t*=r,
// NO LDS twiddle loads; row loads are ds_read_b128 (stride 34 = 16B-align).
// pass 2 (ma-IDFT): tasks (p 4, qa 8, g 32) x4 rounds; outputs {qa, qa+8}
// (+16 via E/O), twiddle chains t=W^{2jqa}, u=W^{(2j+1)qa} stepped by
// r=W^{2qa}; a+8 via (-1)^j / i-rotation (Re/Im of same packed accums).
// LDS ops/task: 135 -> 15. Grid: 2048 = (bq 8) x (zo 256); 256 thr; ~17.7KB.
// ---------------------------------------------------------------------------
__global__ __launch_bounds__(256, 8) void k_inv2(const float2* __restrict__ zhT,
                                                 const float* __restrict__ wiT,
                                                 const float* __restrict__ bias,
                                                 float* __restrict__ out) {
    __shared__ __align__(16) f32x2 Pb[4 * 544];  // plane p at p*544, rows stride 34
    __shared__ f32x2 Wf[32];                     // (cos, sin) 2pi i/32
    int tid = threadIdx.x;
    int zo = blockIdx.x & 255;
    int bq = blockIdx.x >> 8;
    int b0 = bq * 4;
    if (tid < 32) {
        float sv, cv;
        sincosf(6.28318530717958647692f * (float)tid / 32.0f, &sv, &cv);
        f32x2 wv; wv.x = cv; wv.y = sv;
        Wf[tid] = wv;
    }
    // ---- gather: thread = (ng 32, rq 8); 2 ma-rows; 4 betas share each zv
    {
        int ng = tid & 31, rq = tid >> 5;
        int nh = (ng <= 15) ? ng : ng - 32;
        int an = nh < 0 ? -nh : nh;
        const f32x2* zr = (const f32x2*)zhT + (size_t)zo * LTOT;
        const f32x2* wp = (const f32x2*)wiT + (size_t)bq * (LTOT * 2);
#pragma unroll
        for (int mr = 0; mr < 2; mr++) {
            int ma = rq + 8 * mr;
            int l0 = ma > an ? ma : an;
            f32x2 a0 = (f32x2)0.f, a1 = a0, a2 = a0, a3 = a0;
#pragma unroll 4
            for (int l = 0; l < 16; l++) {
                if (l >= l0) {
                    int t = LB[l] + (ma + l) * (2 * l + 1) + (nh + l);
                    f32x2 zv = zr[t];
                    f32x2 w01 = wp[2 * t], w23 = wp[2 * t + 1];
                    a0 = fma_bl(w01, zv, a0);
                    a1 = fma_bh(w01, zv, a1);
                    a2 = fma_bl(w23, zv, a2);
                    a3 = fma_bh(w23, zv, a3);
                }
            }
            int po = ma * 34 + ng;
            Pb[po]            = a0;
            Pb[544 + po]      = a1;
            Pb[2 * 544 + po]  = a2;
            Pb[3 * 544 + po]  = a3;
        }
    }
    __syncthreads();
    // ---- pass 1 (ng -> g): 64 rows x 8 q = 512 tasks over 2 rounds.
    // Row-sharing threads are one wave (lockstep); all reads precede writes
    // in program order, so in-place update stays race-free.
#pragma unroll
    for (int it = 0; it < 2; it++) {
        int task = tid + it * 256;
        int rowid = task >> 3, q = task & 7;
        f32x2* prow = &Pb[(rowid >> 4) * 544 + (rowid & 15) * 34];
        const floatx4* prow4 = (const floatx4*)prow;
        floatx4 eo0 = prow4[0];
        f32x2 Ep; Ep.x = eo0.x; Ep.y = eo0.y;
        f32x2 Op; Op.x = eo0.z; Op.y = eo0.w;
        f32x2 En = (f32x2)0.f, On = (f32x2)0.f;
        f32x2 r = Wf[2 * q];
        f32x2 t = r;
#pragma unroll
        for (int h = 1; h < 16; h++) {
            floatx4 eo = prow4[h];
            f32x2 e; e.x = eo.x; e.y = eo.y;
            f32x2 o; o.x = eo.z; o.y = eo.w;
            if (h & 1) { En = cfma(e, t, En); On = cfma(o, t, On); }
            else       { Ep = cfma(e, t, Ep); Op = cfma(o, t, Op); }
            if (h < 15) t = cmulp(t, r);
        }
        f32x2 E0 = Ep + En, E1 = Ep - En;
        f32x2 O0 = Op + On, O1 = Op - On;
        f32x2 wq = Wf[q];
        f32x2 w0 = cmulp(O0, wq);
        f32x2 u1 = cmulp(O1, wq);
        f32x2 w1; w1.x = -u1.y; w1.y = u1.x;     // i * u1  (W^{q+8} = i W^q)
        prow[q]      = E0 + w0;
        prow[q + 16] = E0 - w0;
        prow[q + 8]  = E1 + w1;
        prow[q + 24] = E1 - w1;
    }
    __syncthreads();
    // ---- pass 2 (ma -> a): tasks (p, qa, g) x4 rounds; direct store + bias
    float bv = bias[zo & 63];
#pragma unroll
    for (int it = 0; it < 4; it++) {
        int task = tid + it * 256;
        int p = task >> 8, rr = task & 255;
        int qa = rr >> 5, g = rr & 31;
        const f32x2* pc = &Pb[p * 544];
        f32x2 r = Wf[2 * qa];
        f32x2 u = Wf[qa];
        f32x2 Uee = (f32x2)0.f, Ueo = Uee, Ve = Uee, Vo = Uee;
        f32x2 c0 = pc[g];
        {   // j = 0: odd column only
            f32x2 c1 = pc[34 + g];
            Ve = cfma(c1, u, Ve);
        }
        f32x2 t = r;
        u = cmulp(u, r);
#pragma unroll
        for (int j = 1; j < 8; j++) {
            f32x2 ce = pc[(2 * j) * 34 + g];
            f32x2 co = pc[(2 * j + 1) * 34 + g];
            if (j & 1) { Ueo = cfma(ce, t, Ueo); Vo = cfma(co, u, Vo); }
            else       { Uee = cfma(ce, t, Uee); Ve = cfma(co, u, Ve); }
            if (j < 7) { t = cmulp(t, r); u = cmulp(u, r); }
        }
        float EaA = c0.x + 2.f * (Uee.x + Ueo.x);
        float EaB = c0.x + 2.f * (Uee.x - Ueo.x);
        float OaA = 2.f * (Ve.x + Vo.x);
        float OaB = -2.f * (Ve.y - Vo.y);
        float* dst = out + (size_t)zo * 32768 + (size_t)(b0 + p) * 1024;
        constexpr float sc = 1.f / 1024.f;
        dst[qa * 32 + g]         = (EaA + OaA) * sc + bv;
        dst[(qa + 16) * 32 + g]  = (EaA - OaA) * sc + bv;
        dst[(qa + 8) * 32 + g]   = (EaB + OaB) * sc + bv;
        dst[(qa + 24) * 32 + g]  = (EaB - OaB) * sc + bv;
    }
}

// ---------------------------------------------------------------------------
extern "C" void kernel_launch(void* const* d_in, const int* in_sizes, int n_in,
                              void* d_out, int out_size, void* d_ws, size_t ws_size,
                              hipStream_t stream) {
    const float* x    = (const float*)d_in[0];
    const float* ker  = (const float*)d_in[1];
    const float* bias = (const float*)d_in[2];
    const float* wf   = (const float*)d_in[3];
    const float* wi   = (const float*)d_in[4];
    const float* Dre  = (const float*)d_in[5];
    const float* Dim  = (const float*)d_in[6];
    float* out = (float*)d_out;

    // layout: yhb 44.7MB | Ab 4.2MB | zh_T 11.2MB.
    // Xfb (8.4MB) + wfT (698KB, at zhT+8.39MB) alias zh_T: both dead once
    // k_gemm writes zhT. wiT (698KB) aliases yhb base: written after k_gemm
    // (yhb dead), read by k_inv2.
    char* ws = (char*)d_ws;
    u32*    yhb = (u32*)ws;
    u16*    Ab  = (u16*)(ws + 44695552);
    float*  zhT = (float*)(ws + 44695552 + 4194304);
    u32*    Xfb = (u32*)zhT;                                    // disjoint lifetime vs zh_T
    float*  wfT = (float*)(ws + 44695552 + 4194304 + 8388608);  // zhT tail, pre-gemm
    float*  wiT = (float*)ws;                                   // yhb region, post-gemm

    hipLaunchKernelGGL(k_fft_fwd, dim3(4096),  dim3(512), 0, stream, x, Xfb);
    hipLaunchKernelGGL(k_wtr,     dim3(22, 8), dim3(256), 0, stream, wf, wfT);
    hipLaunchKernelGGL(k_prep_B,  dim3(682),   dim3(256), 0, stream, Dre, Dim, ker, yhb);
    hipLaunchKernelGGL(k_beta_A,  dim3(2048),  dim3(256), 0, stream, Xfb, wfT, Ab);
    hipLaunchKernelGGL(k_gemm,    dim3(1024),  dim3(256), 0, stream, Ab, yhb, zhT);
    hipLaunchKernelGGL(k_wtr,     dim3(22, 8), dim3(256), 0, stream, wi, wiT);
    hipLaunchKernelGGL(k_inv2,    dim3(2048),  dim3(256), 0, stream,
                       (const float2*)zhT, wiT, bias, out);
}